// Round 8
// baseline (218.045 us; speedup 1.0000x reference)
//
#include <hip/hip_runtime.h>
#include <hip/hip_bf16.h>
#include <hip/hip_fp16.h>
#include <stdint.h>
#include <stddef.h>

typedef __attribute__((ext_vector_type(8))) short short8;
typedef __attribute__((ext_vector_type(4))) float f32x4;
typedef __attribute__((ext_vector_type(2))) float f32x2;
typedef unsigned short ushort_t;

#define NHEADS 16
#define HD 32
#define NQ 740
#define NB 16
#define MROWS (NB*NQ)       // 11840
#define CD 512
#define KDIM 512
#define VSTRIDE 768         // v^T row stride
#define NQT 48              // padded q-tile slots for bias
#define PTS 40              // P[q][key] stride in bf16 (32 keys + 8 pad)
#define QS2 0.2550400865f   // hd^-0.5 * log2(e)
#define LOG2E 1.4426950409f
#define NEG_BIG -43000.0f   // log2e-scaled mask; v_exp_f32 flushes to 0

static __device__ __forceinline__ void gld_lds16(const void* g, void* l) {
    __builtin_amdgcn_global_load_lds((const __attribute__((address_space(1))) void*)g,
                                     (__attribute__((address_space(3))) void*)l,
                                     16, 0, 0);
}

static __device__ __forceinline__ float ldf(const void* p, int i, int fl) {
    return fl ? ((const float*)p)[i] : (float)((const __hip_bfloat16*)p)[i];
}
static __device__ __forceinline__ ushort_t f2bf(float f) {
    __hip_bfloat16 h(f);
    return *reinterpret_cast<ushort_t*>(&h);
}
static __device__ __forceinline__ float fexp2(float x) {
#if __has_builtin(__builtin_amdgcn_exp2f)
    return __builtin_amdgcn_exp2f(x);
#else
    return exp2f(x);
#endif
}
// f32 -> e5m2 byte (RNE via fp16; e5m2 == fp16 top byte)
static __device__ __forceinline__ unsigned int f2e5(float f) {
    __half h = __float2half(f);
    unsigned short hb = *reinterpret_cast<unsigned short*>(&h);
    return (((unsigned int)hb + 0x7fu + ((hb >> 8) & 1u)) >> 8) & 0xffu;
}
// 4 packed e5m2 -> f32x4. gfx950: HW v_cvt_pk_f32_bf8 (OCP e5m2 == fp16 top byte)
#if __has_builtin(__builtin_amdgcn_cvt_pk_f32_bf8)
static __device__ __forceinline__ f32x4 bias4f8(unsigned int b) {
    f32x2 lo = __builtin_amdgcn_cvt_pk_f32_bf8((int)b, false);
    f32x2 hi = __builtin_amdgcn_cvt_pk_f32_bf8((int)b, true);
    f32x4 c;
    c[0] = lo[0]; c[1] = lo[1]; c[2] = hi[0]; c[3] = hi[1];
    return c;
}
#else
static __device__ __forceinline__ f32x4 bias4f8(unsigned int b) {
    f32x4 c;
    #pragma unroll
    for (int i = 0; i < 4; ++i) {
        union { unsigned short u; __half h; } cv;
        cv.u = (unsigned short)(((b >> (8 * i)) & 0xffu) << 8);
        c[i] = __half2float(cv.h);
    }
    return c;
}
#endif
// pack f32x4 -> 4 bf16 (RNE, packed HW cvt), single 8B LDS store
static __device__ __forceinline__ void pkstore(__hip_bfloat16* dst, f32x4 c) {
    __hip_bfloat162* d = (__hip_bfloat162*)dst;
    d[0] = __float22bfloat162_rn(make_float2(c[0], c[1]));
    d[1] = __float22bfloat162_rn(make_float2(c[2], c[3]));
}
static __device__ __forceinline__ uint2 pk4(float a, float b, float c, float d) {
    __hip_bfloat162 p01 = __float22bfloat162_rn(make_float2(a, b));
    __hip_bfloat162 p23 = __float22bfloat162_rn(make_float2(c, d));
    uint2 u;
    u.x = *reinterpret_cast<unsigned int*>(&p01);
    u.y = *reinterpret_cast<unsigned int*>(&p23);
    return u;
}

// ------------- dtype sniff: fp32 arrays have uniform low-16 mantissa bits ----
__global__ __launch_bounds__(64) void sniff_k(const unsigned int* __restrict__ w,
                                              int* __restrict__ flag) {
    int cnt = 0;
    for (int i = threadIdx.x; i < 1024; i += 64) {
        unsigned int e = (w[i] >> 7) & 0xFFu;
        cnt += (e > 135u) ? 1 : 0;
    }
    #pragma unroll
    for (int d = 1; d < 64; d <<= 1) cnt += __shfl_xor(cnt, d);
    if (threadIdx.x == 0) *flag = (cnt > 16) ? 1 : 0;
}

// ------- merged prep: convx | transpose Wqkv | transpose Wproj | biasF -------
// All bodies read only kernel inputs -> no cross-deps; one launch replaces 4.
#define PREP_CONV 1480
#define PREP_TA   768     // Wqkv transpose: 48 x 16
#define PREP_TB   256     // Wproj transpose: 16 x 16
#define PREP_BIAS 768     // biasF: 16*48
__global__ __launch_bounds__(256) void prep_k(
    const void* __restrict__ x, ushort4* __restrict__ Xb,
    const void* __restrict__ Wqkv, __hip_bfloat16* __restrict__ WqT,
    const void* __restrict__ Wproj, __hip_bfloat16* __restrict__ WpT,
    const void* __restrict__ btT, const void* __restrict__ btt,
    const void* __restrict__ ttab, const void* __restrict__ tgtab,
    const void* __restrict__ ttln, const void* __restrict__ tgln,
    unsigned int* __restrict__ biasF,
    const int* __restrict__ flag) {
    __shared__ __hip_bfloat16 tile[32][33];
    const int bid = blockIdx.x;
    const int tid = threadIdx.x;
    const int fl = *flag;

    if (bid < PREP_CONV) {
        const int n = MROWS * CD / 4;
        for (int i = bid * 256 + tid; i < n; i += PREP_CONV * 256) {
            if (fl) {
                float4 v = ((const float4*)x)[i];
                ushort4 o;
                o.x = f2bf(v.x); o.y = f2bf(v.y); o.z = f2bf(v.z); o.w = f2bf(v.w);
                Xb[i] = o;
            } else {
                Xb[i] = ((const ushort4*)x)[i];
            }
        }
        return;
    }
    if (bid < PREP_CONV + PREP_TA + PREP_TB) {
        const void* src; __hip_bfloat16* dst; int R, C, lb;
        if (bid < PREP_CONV + PREP_TA) {
            src = Wqkv; dst = WqT; R = 512; C = 1536; lb = bid - PREP_CONV;
        } else {
            src = Wproj; dst = WpT; R = 512; C = 512; lb = bid - PREP_CONV - PREP_TA;
        }
        int nbx = C / 32;
        int bx = (lb % nbx) * 32;
        int by = (lb / nbx) * 32;
        int tx = tid & 31, ty = tid >> 5;
        for (int r = ty; r < 32; r += 8)
            tile[r][tx] = __hip_bfloat16(ldf(src, (by + r) * C + bx + tx, fl));
        __syncthreads();
        for (int r = ty; r < 32; r += 8)
            dst[(size_t)(bx + r) * R + by + tx] = tile[tx][r];
        return;
    }
    // biasF: [blk=hh*48+qt][kb 48][lane 64] e5m2-packed uint
    const int blk = bid - (PREP_CONV + PREP_TA + PREP_TB);
    const int hh = blk / NQT;
    const int qt = blk - hh * NQT;
    for (int idx = tid; idx < 48 * 64; idx += 256) {
        const int lane = idx & 63;
        const int kb = idx >> 6;
        const int lr = lane & 15, kc = lane >> 4;
        int i = qt * 16 + lr; if (i > NQ - 1) i = NQ - 1;
        unsigned int pk = 0;
        #pragma unroll
        for (int r = 0; r < 4; ++r) {
            int c = kb * 16 + kc * 4 + r;
            float v;
            if (c >= NQ) {
                v = NEG_BIG;
            } else if (i < 256) {
                if (c < 256) {
                    int t = ((i >> 4) - (c >> 4) + 15) * 31 + ((i & 15) - (c & 15) + 15);
                    v = ldf(btt, t * 16 + hh, fl) * LOG2E;
                } else {
                    v = (ldf(tgtab, hh * 256 + i, fl) + ldf(tgln, hh * 484 + (c - 256), fl)) * LOG2E;
                }
            } else {
                int ii = i - 256;
                if (c < 256) {
                    v = (ldf(ttab, hh * 484 + ii, fl) + ldf(ttln, hh * 256 + c, fl)) * LOG2E;
                } else {
                    int jj = c - 256;
                    int a = ii / 22, b2 = ii - a * 22;
                    int a2 = jj / 22, b3 = jj - a2 * 22;
                    int t = (a - a2 + 21) * 43 + (b2 - b3 + 21);
                    v = ldf(btT, t * 16 + hh, fl) * LOG2E;
                }
            }
            pk |= f2e5(v) << (8 * r);
        }
        biasF[(size_t)blk * 48 * 64 + idx] = pk;
    }
}

// ------- qkv GEMM: 256x128 tile, 2-buf depth-1 (textbook drain) -------------
// Round-7 profile: 72KB LDS caps residency at 2 blocks/CU -> 512 slots for a
// 564-block grid (52-block straggler wave on an idle machine; Occupancy 12%).
// v15: 2 buffers (48KB) -> 3 blocks/CU, ALL 564 blocks co-resident, zero
// tail, 12 waves/CU. Sync is strictly MORE conservative than before: full
// vmcnt(0)+lgkm(0) drain + barrier per K-step (m97 pattern). Staging
// addresses, layout, MFMA order, epilogue (still at +24576 = buffer 1)
// byte-identical.
__global__ __launch_bounds__(256) void gemm_qkv(
    const __hip_bfloat16* __restrict__ A,
    const __hip_bfloat16* __restrict__ Bt,
    const void* __restrict__ biasv,
    __hip_bfloat16* __restrict__ Qw,
    __hip_bfloat16* __restrict__ Kw,
    __hip_bfloat16* __restrict__ Vtw,
    const int* __restrict__ flag) {
    __shared__ __attribute__((aligned(16))) short sStage[2 * 12288];  // 48 KB
    const int tid = threadIdx.x;
    const int lane = tid & 63;
    const int wv = tid >> 6;
    const int lr = lane & 15, kc = lane >> 4;
    const int m0 = blockIdx.y * 256;
    const int n0 = blockIdx.x * 128;
    const int fl = *flag;
    const int M = MROWS;

    auto stage = [&](int s) {
        char* bb = (char*)sStage + (s & 1) * 24576;
        const int k0 = s * 32;
        #pragma unroll
        for (int it = 0; it < 6; ++it) {
            int idx = it * 256 + tid;
            if (idx < 1024) {
                int r = idx >> 2, c = idx & 3;
                int gr = m0 + r; if (gr > M - 1) gr = M - 1;
                gld_lds16(A + (size_t)gr * KDIM + k0 + c * 8, bb + idx * 16);
            } else {
                int u = idx - 1024;
                int r = u >> 2, c = u & 3;
                gld_lds16(Bt + (size_t)(n0 + r) * KDIM + k0 + c * 8, bb + 16384 + u * 16);
            }
        }
    };

    f32x4 acc[4][8] = {};
    stage(0);
    asm volatile("" ::: "memory");
    __builtin_amdgcn_s_waitcnt(0x0070);   // vmcnt(0) lgkm(0)
    __builtin_amdgcn_s_barrier();
    asm volatile("" ::: "memory");

    for (int ks = 0; ks < 16; ++ks) {
        if (ks + 1 < 16) stage(ks + 1);   // writes buf (ks+1)&1, read last in ks-1 (pre-barrier)
        asm volatile("" ::: "memory");

        const char* bb = (const char*)sStage + (ks & 1) * 24576;
        const short* cA = (const short*)bb;
        const short* cB = (const short*)(bb + 16384);
        short8 af[4], bfr[8];
        #pragma unroll
        for (int t = 0; t < 4; ++t)
            af[t] = *(const short8*)&cA[(wv * 64 + t * 16 + lr) * 32 + kc * 8];
        #pragma unroll
        for (int t = 0; t < 8; ++t)
            bfr[t] = *(const short8*)&cB[(t * 16 + lr) * 32 + kc * 8];
        #pragma unroll
        for (int i = 0; i < 4; ++i)
            #pragma unroll
            for (int j = 0; j < 8; ++j)
                acc[i][j] = __builtin_amdgcn_mfma_f32_16x16x32_bf16(af[i], bfr[j], acc[i][j], 0, 0, 0);

        asm volatile("" ::: "memory");
        __builtin_amdgcn_s_waitcnt(0x0070);   // vmcnt(0) lgkm(0): full drain
        __builtin_amdgcn_s_barrier();
        asm volatile("" ::: "memory");
    }

    // ---- epilogue: LDS repack (buffer 1) -> coalesced global stores ----
    const int s = n0 >> 9;
    short* Tw = (short*)((char*)sStage + 24576) + wv * 2560;
    const int gmr = m0 + wv * 64 + lane;
    int gmrc = gmr < M ? gmr : M - 1;
    int bq = gmrc / NQ;
    int nnq = gmrc - bq * NQ;
    const int gmv = m0 + wv * 64 + (lane & 15) * 4;
    int gmvc = gmv < M ? gmv : M - 1;
    int bv2 = gmvc / NQ;
    int nnv = gmvc - bv2 * NQ;

    #pragma unroll
    for (int t = 0; t < 4; ++t) {
        const int hh = ((n0 >> 5) + t) & 15;
        float bva = ldf(biasv, n0 + t * 32 + lr, fl);
        float bvb = ldf(biasv, n0 + t * 32 + 16 + lr, fl);
        asm volatile("" ::: "memory");
        if (s == 2) {
            #pragma unroll
            for (int i = 0; i < 4; ++i) {
                int nl = i * 16 + kc * 4;
                uint2 ua = pk4(acc[i][2*t][0] + bva, acc[i][2*t][1] + bva,
                               acc[i][2*t][2] + bva, acc[i][2*t][3] + bva);
                uint2 ub = pk4(acc[i][2*t+1][0] + bvb, acc[i][2*t+1][1] + bvb,
                               acc[i][2*t+1][2] + bvb, acc[i][2*t+1][3] + bvb);
                *(uint2*)(void*)&Tw[lr * 72 + nl]        = ua;
                *(uint2*)(void*)&Tw[(16 + lr) * 72 + nl] = ub;
            }
        } else {
            float sc = (s == 0) ? QS2 : 1.0f;
            #pragma unroll
            for (int i = 0; i < 4; ++i)
                #pragma unroll
                for (int r = 0; r < 4; ++r) {
                    int nl = i * 16 + kc * 4 + r;
                    Tw[nl * 40 + lr]      = (short)f2bf((acc[i][2*t][r]   + bva) * sc);
                    Tw[nl * 40 + 16 + lr] = (short)f2bf((acc[i][2*t+1][r] + bvb) * sc);
                }
        }
        asm volatile("" ::: "memory");
        __builtin_amdgcn_s_waitcnt(0xc07f);
        asm volatile("" ::: "memory");
        if (s == 2) {
            if (gmv < M) {
                size_t bh = (size_t)(bv2 * 16 + hh);
                #pragma unroll
                for (int i2 = 0; i2 < 8; ++i2) {
                    int d = (lane >> 4) + i2 * 4;
                    uint2 u = *(const uint2*)(const void*)&Tw[d * 72 + (lane & 15) * 4];
                    *(uint2*)(void*)(Vtw + (bh * HD + d) * VSTRIDE + nnv) = u;
                }
            }
        } else {
            if (gmr < M) {
                size_t bh = (size_t)(bq * 16 + hh);
                __hip_bfloat16* dst = (s == 0 ? Qw : Kw) + (bh * NQ + nnq) * HD;
                #pragma unroll
                for (int c = 0; c < 4; ++c) {
                    short8 u = *(const short8*)(const void*)&Tw[lane * 40 + c * 8];
                    *(short8*)(void*)(dst + c * 8) = u;
                }
            }
        }
        asm volatile("" ::: "memory");
        __builtin_amdgcn_s_waitcnt(0xc07f);
        asm volatile("" ::: "memory");
    }
}

// ----- proj GEMM: 128x128, PIPELINED K-loop (3-buf, depth-2): Out=A@Bt^T+bias
__global__ __launch_bounds__(256) void gemm_bt(
    const __hip_bfloat16* __restrict__ A,
    const __hip_bfloat16* __restrict__ Bt,
    const void* __restrict__ biasv,
    int M,
    __hip_bfloat16* __restrict__ Out,
    float* __restrict__ OutF,
    const int* __restrict__ flag) {
    __shared__ __attribute__((aligned(16))) short sStage[3 * 8192];   // 48 KB
    const int tid = threadIdx.x;
    const int lane = tid & 63;
    const int wv = tid >> 6;
    const int wr = wv >> 1, wc = wv & 1;
    const int lr = lane & 15, kc = lane >> 4;
    const int m0 = blockIdx.y * 128;
    const int n0 = blockIdx.x * 128;
    const int fl = *flag;

    auto stage = [&](int s) {
        char* bb = (char*)sStage + (s % 3) * 16384;
        const int k0 = s * 32;
        #pragma unroll
        for (int it = 0; it < 2; ++it) {
            int idx = it * 256 + tid;
            int r = idx >> 2;
            int c = idx & 3;
            int gr = m0 + r; if (gr > M - 1) gr = M - 1;
            gld_lds16(A + (size_t)gr * KDIM + k0 + c * 8, bb + idx * 16);
            gld_lds16(Bt + (size_t)(n0 + r) * KDIM + k0 + c * 8, bb + 8192 + idx * 16);
        }
    };

    f32x4 acc[4][4] = {};
    stage(0);
    stage(1);

    for (int ks = 0; ks < 16; ++ks) {
        asm volatile("" ::: "memory");
        if (ks < 15) __builtin_amdgcn_s_waitcnt(0x0074);  // vmcnt(4) lgkm(0)
        else         __builtin_amdgcn_s_waitcnt(0x0070);
        __builtin_amdgcn_s_barrier();
        asm volatile("" ::: "memory");
        if (ks + 2 < 16) stage(ks + 2);

        const char* bb = (const char*)sStage + (ks % 3) * 16384;
        const short* cA = (const short*)bb;
        const short* cB = (const short*)(bb + 8192);
        short8 af[4], bfr[4];
        #pragma unroll
        for (int t = 0; t < 4; ++t)
            af[t] = *(const short8*)&cA[(wr * 64 + t * 16 + lr) * 32 + kc * 8];
        #pragma unroll
        for (int t = 0; t < 4; ++t)
            bfr[t] = *(const short8*)&cB[(wc * 64 + t * 16 + lr) * 32 + kc * 8];
        #pragma unroll
        for (int i = 0; i < 4; ++i)
            #pragma unroll
            for (int j = 0; j < 4; ++j)
                acc[i][j] = __builtin_amdgcn_mfma_f32_16x16x32_bf16(af[i], bfr[j], acc[i][j], 0, 0, 0);
    }

    #pragma unroll
    for (int i = 0; i < 4; ++i) {
        #pragma unroll
        for (int j = 0; j < 4; ++j) {
            int gn = n0 + wc * 64 + j * 16 + lr;
            float bv = ldf(biasv, gn, fl);
            #pragma unroll
            for (int r = 0; r < 4; ++r) {
                int gm = m0 + wr * 64 + i * 16 + kc * 4 + r;
                if (gm < M) {
                    float v = acc[i][j][r] + bv;
                    if (fl) OutF[(size_t)gm * CD + gn] = v;
                    else    Out[(size_t)gm * CD + gn] = __hip_bfloat16(v);
                }
            }
        }
    }
}

// ---- fused attention v14: v9 sync skeleton, 64 q-rows per wave (VERIFIED) --
__global__ __launch_bounds__(256, 3) void attn_k(
    const __hip_bfloat16* __restrict__ Qw,
    const __hip_bfloat16* __restrict__ Kw,
    const __hip_bfloat16* __restrict__ Vtw,
    const unsigned int* __restrict__ biasF,
    __hip_bfloat16* __restrict__ AO) {
    __shared__ __attribute__((aligned(16))) short sStage[3 * 2048];        // 12 KB
    __shared__ __attribute__((aligned(16))) __hip_bfloat16 Pt[4][64 * PTS]; // 20.5 KB

    const int tid = threadIdx.x;
    const int wv = tid >> 6;
    const int p = blockIdx.x * 4 + wv;       // 0..11: 64 q-rows per wave
    const int bh = blockIdx.y;               // b*16 + h
    const int hh = bh & 15;
    const int b = bh >> 4;
    const int q0 = p * 64;
    const int lane = tid & 63;
    const int lr = lane & 15, kc = lane >> 4;

    const __hip_bfloat16* Qb = Qw + (size_t)bh * NQ * HD;
    const __hip_bfloat16* Kb = Kw + (size_t)bh * NQ * HD;
    const __hip_bfloat16* Vb = Vtw + (size_t)bh * HD * VSTRIDE;
    __hip_bfloat16* Pw = &Pt[wv][0];

    short8 qfA = *(const short8*)(const void*)(Qb + (q0 + lr) * HD + kc * 8);
    short8 qfB = *(const short8*)(const void*)(Qb + (q0 + 16 + lr) * HD + kc * 8);
    short8 qfC = *(const short8*)(const void*)(Qb + (q0 + 32 + lr) * HD + kc * 8);
    short8 qfD = *(const short8*)(const void*)(Qb + (q0 + 48 + lr) * HD + kc * 8);

    short8 onesf;
    {
        short s1 = (lr == 0) ? (short)0x3F80 : (short)0;
        #pragma unroll
        for (int j = 0; j < 8; ++j) onesf[j] = s1;
    }

    // bias slices for the wave's 4 q-16-tiles: 4p+0..4p+3 (<= 47 < NQT)
    const unsigned int* bt0 = biasF + (size_t)(hh * NQT + 4 * p) * 48 * 64 + lane;
    const unsigned int* bt1 = bt0 + 48 * 64;
    const unsigned int* bt2 = bt0 + 2 * 48 * 64;
    const unsigned int* bt3 = bt0 + 3 * 48 * 64;

    unsigned int brA0[2], brA1[2], brB0[2], brB1[2];
    unsigned int brC0[2], brC1[2], brD0[2], brD1[2];
    brA0[0] = bt0[0];  brA1[0] = bt0[64];
    brB0[0] = bt1[0];  brB1[0] = bt1[64];
    brC0[0] = bt2[0];  brC1[0] = bt2[64];
    brD0[0] = bt3[0];  brD1[0] = bt3[64];

    // staging: [unit 4][row 32] blocks (transposed lane mapping). K: lanes
    // 0..127 (row=l&31, unit=l>>5); V: lanes 128..255 (d=u&31, unit=u>>5).
    // IDENTICAL to v9 (verified).
    {
        const void* src;
        if (tid < 128) src = Kb + (tid & 31) * HD + (tid >> 5) * 8;
        else { int u = tid - 128; src = Vb + (u & 31) * VSTRIDE + ((u >> 5) & 3) * 8; }
        gld_lds16(src, (char*)sStage + tid * 16);
    }
    asm volatile("" ::: "memory");

    f32x4 oa0 = {}, ob0 = {}, ol0 = {};
    f32x4 oa1 = {}, ob1 = {}, ol1 = {};
    f32x4 oa2 = {}, ob2 = {}, ol2 = {};
    f32x4 oa3 = {}, ob3 = {}, ol3 = {};

    #pragma unroll
    for (int ks = 0; ks < 24; ++ks) {
        const int cur = ks & 1, nxt = cur ^ 1;
        if (ks < 23) {
            brA0[nxt] = bt0[(2 * ks + 2) * 64];
            brA1[nxt] = bt0[(2 * ks + 3) * 64];
            brB0[nxt] = bt1[(2 * ks + 2) * 64];
            brB1[nxt] = bt1[(2 * ks + 3) * 64];
            brC0[nxt] = bt2[(2 * ks + 2) * 64];
            brC1[nxt] = bt2[(2 * ks + 3) * 64];
            brD0[nxt] = bt3[(2 * ks + 2) * 64];
            brD1[nxt] = bt3[(2 * ks + 3) * 64];
            const int k0n = (ks + 1) * 32;
            const int nb = ((ks + 1) % 3) * 4096;
            const void* src;
            if (tid < 128) src = Kb + (k0n + (tid & 31)) * HD + (tid >> 5) * 8;
            else { int u = tid - 128; src = Vb + (u & 31) * VSTRIDE + k0n + ((u >> 5) & 3) * 8; }
            gld_lds16(src, (char*)sStage + nb + tid * 16);
        }
        asm volatile("" ::: "memory");
        if (ks < 23) __builtin_amdgcn_s_waitcnt(0x0F79);   // vmcnt(9): bias(ks+1)8+stage(ks+1)1
        else         __builtin_amdgcn_s_waitcnt(0x0F70);   // vmcnt(0)
        __builtin_amdgcn_s_barrier();
        asm volatile("" ::: "memory");

        const short* sK = (const short*)((const char*)sStage + (ks % 3) * 4096);
        const short* sV = sK + 1024;
        // [unit][row]: addr = kc*256 + row*8 shorts -> 2-way banks (free)
        short8 kf0 = *(const short8*)&sK[kc * 256 + lr * 8];
        short8 kf1 = *(const short8*)&sK[kc * 256 + (16 + lr) * 8];
        short8 vf0 = *(const short8*)&sV[kc * 256 + lr * 8];
        short8 vf1 = *(const short8*)&sV[kc * 256 + (16 + lr) * 8];

        // ---- q-set 1 (tiles 4p, 4p+1) ----
        {
            f32x4 c0 = bias4f8(brA0[cur]);
            f32x4 c1 = bias4f8(brA1[cur]);
            f32x4 c2 = bias4f8(brB0[cur]);
            f32x4 c3 = bias4f8(brB1[cur]);

            c0 = __builtin_amdgcn_mfma_f32_16x16x32_bf16(kf0, qfA, c0, 0, 0, 0);
            c1 = __builtin_amdgcn_mfma_f32_16x16x32_bf16(kf1, qfA, c1, 0, 0, 0);
            c2 = __builtin_amdgcn_mfma_f32_16x16x32_bf16(kf0, qfB, c2, 0, 0, 0);
            c3 = __builtin_amdgcn_mfma_f32_16x16x32_bf16(kf1, qfB, c3, 0, 0, 0);

            #pragma unroll
            for (int r = 0; r < 4; ++r) {
                c0[r] = fexp2(c0[r]); c1[r] = fexp2(c1[r]);
                c2[r] = fexp2(c2[r]); c3[r] = fexp2(c3[r]);
            }
            pkstore(Pw + lr * PTS + kc * 4, c0);
            pkstore(Pw + lr * PTS + 16 + kc * 4, c1);
            pkstore(Pw + (16 + lr) * PTS + kc * 4, c2);
            pkstore(Pw + (16 + lr) * PTS + 16 + kc * 4, c3);
        }
        // ---- q-set 2 (tiles 4p+2, 4p+3) ----
        {
            f32x4 c0 = bias4f8(brC0[cur]);
            f32x4 c1 = bias4f8(brC1[cur]);
            f32x4 c2 = bias4f8(brD0[cur]);
            f32x4 c3 = bias4f8(brD1[cur]);

            c0 = __builtin_amdgcn_mfma_f32_16x16x32_bf16(kf0, qfC, c0, 0, 0, 0);
            c1 = __builtin_amdgcn_mfma_f32_16x16x32_bf16(kf1, qfC, c1, 0, 0, 0);
            c2 = __builtin_amdgcn_mfma_f32_16x16x32_bf16(kf0, qfD, c2, 0, 0, 0);
            c3 = __builtin_amdgcn_mfma_f32_16x16x32_bf16(kf1, qfD, c3, 0, 0, 0);

            #pragma unroll
            for (int r = 0; r < 4; ++r) {
                c0[r] = fexp2(c0[r]); c1[r] = fexp2(c1[r]);
                c2[r] = fexp2(c2[r]); c3[r] = fexp2(c3[r]);
            }
            pkstore(Pw + (32 + lr) * PTS + kc * 4, c0);
            pkstore(Pw + (32 + lr) * PTS + 16 + kc * 4, c1);
            pkstore(Pw + (48 + lr) * PTS + kc * 4, c2);
            pkstore(Pw + (48 + lr) * PTS + 16 + kc * 4, c3);
        }
        asm volatile("" ::: "memory");
        __builtin_amdgcn_s_waitcnt(0xc07f);   // lgkmcnt(0)
        asm volatile("" ::: "memory");

        short8 pfA = *(const short8*)(const void*)(Pw + lr * PTS + kc * 8);
        short8 pfB = *(const short8*)(const void*)(Pw + (16 + lr) * PTS + kc * 8);
        short8 pfC = *(const short8*)(const void*)(Pw + (32 + lr) * PTS + kc * 8);
        short8 pfD = *(const short8*)(const void*)(Pw + (48 + lr) * PTS + kc * 8);

        oa0 = __builtin_amdgcn_mfma_f32_16x16x32_bf16(pfA, vf0, oa0, 0, 0, 0);
        ob0 = __builtin_amdgcn_mfma_f32_16x16x32_bf16(pfA, vf1, ob0, 0, 0, 0);
        ol0 = __builtin_amdgcn_mfma_f32_16x16x32_bf16(pfA, onesf, ol0, 0, 0, 0);
        oa1 = __builtin_amdgcn_mfma_f32_16x16x32_bf16(pfB, vf0, oa1, 0, 0, 0);
        ob1 = __builtin_amdgcn_mfma_f32_16x16x32_bf16(pfB, vf1, ob1, 0, 0, 0);
        ol1 = __builtin_amdgcn_mfma_f32_16x16x32_bf16(pfB, onesf, ol1, 0, 0, 0);
        oa2 = __builtin_amdgcn_mfma_f32_16x16x32_bf16(pfC, vf0, oa2, 0, 0, 0);
        ob2 = __builtin_amdgcn_mfma_f32_16x16x32_bf16(pfC, vf1, ob2, 0, 0, 0);
        ol2 = __builtin_amdgcn_mfma_f32_16x16x32_bf16(pfC, onesf, ol2, 0, 0, 0);
        oa3 = __builtin_amdgcn_mfma_f32_16x16x32_bf16(pfD, vf0, oa3, 0, 0, 0);
        ob3 = __builtin_amdgcn_mfma_f32_16x16x32_bf16(pfD, vf1, ob3, 0, 0, 0);
        ol3 = __builtin_amdgcn_mfma_f32_16x16x32_bf16(pfD, onesf, ol3, 0, 0, 0);
    }

    #pragma unroll
    for (int r = 0; r < 4; ++r) {
        int row = kc * 4 + r;
        float lA = __shfl(ol0[r], lane & 48);
        float lB = __shfl(ol1[r], lane & 48);
        float lC = __shfl(ol2[r], lane & 48);
        float lD = __shfl(ol3[r], lane & 48);
        float liA = 1.0f / lA, liB = 1.0f / lB;
        float liC = 1.0f / lC, liD = 1.0f / lD;
        int orA = q0 + row, orB = q0 + 16 + row;
        int orC = q0 + 32 + row, orD = q0 + 48 + row;
        if (orA < NQ) {
            size_t base = ((size_t)b * NQ + orA) * CD + hh * HD;
            AO[base + lr]      = __hip_bfloat16(oa0[r] * liA);
            AO[base + 16 + lr] = __hip_bfloat16(ob0[r] * liA);
        }
        if (orB < NQ) {
            size_t base = ((size_t)b * NQ + orB) * CD + hh * HD;
            AO[base + lr]      = __hip_bfloat16(oa1[r] * liB);
            AO[base + 16 + lr] = __hip_bfloat16(ob1[r] * liB);
        }
        if (orC < NQ) {
            size_t base = ((size_t)b * NQ + orC) * CD + hh * HD;
            AO[base + lr]      = __hip_bfloat16(oa2[r] * liC);
            AO[base + 16 + lr] = __hip_bfloat16(ob2[r] * liC);
        }
        if (orD < NQ) {
            size_t base = ((size_t)b * NQ + orD) * CD + hh * HD;
            AO[base + lr]      = __hip_bfloat16(oa3[r] * liD);
            AO[base + 16 + lr] = __hip_bfloat16(ob3[r] * liD);
        }
    }
}

extern "C" void kernel_launch(void* const* d_in, const int* in_sizes, int n_in,
                              void* d_out, int out_size, void* d_ws, size_t ws_size,
                              hipStream_t stream) {
    char* ws = (char*)d_ws;
    size_t off = 0;
    auto carve = [&](size_t bytes) {
        char* p = ws + off;
        off += (bytes + 255) & ~(size_t)255;
        return p;
    };
    int* flagp = (int*)carve(256);
    __hip_bfloat16* Qw    = (__hip_bfloat16*)carve((size_t)256 * NQ * HD * 2);
    __hip_bfloat16* Kw    = (__hip_bfloat16*)carve((size_t)256 * NQ * HD * 2);
    __hip_bfloat16* Vtw   = (__hip_bfloat16*)carve((size_t)256 * HD * VSTRIDE * 2);
    __hip_bfloat16* WqT   = (__hip_bfloat16*)carve((size_t)1536 * 512 * 2);
    __hip_bfloat16* WpT   = (__hip_bfloat16*)carve((size_t)512 * 512 * 2);
    unsigned int*   biasF = (unsigned int*)carve((size_t)16 * NQT * 48 * 64 * 4);
    __hip_bfloat16* Xb    = (__hip_bfloat16*)carve((size_t)MROWS * CD * 2);
    __hip_bfloat16* AO    = Xb;   // attn output overwrites x-staging (dead after qkv gemm)
    (void)ws_size; (void)in_sizes; (void)n_in; (void)out_size;

    sniff_k<<<dim3(1), dim3(64), 0, stream>>>((const unsigned int*)d_in[1], flagp);
    prep_k<<<dim3(PREP_CONV + PREP_TA + PREP_TB + PREP_BIAS), dim3(256), 0, stream>>>(
        d_in[0], (ushort4*)Xb, d_in[1], WqT, d_in[3], WpT,
        d_in[5], d_in[6], d_in[7], d_in[8], d_in[9], d_in[10], biasF, flagp);
    gemm_qkv<<<dim3(12, 47), dim3(256), 0, stream>>>(Xb, WqT, d_in[2],
        Qw, Kw, Vtw, flagp);
    attn_k<<<dim3(3, 256), dim3(256), 0, stream>>>(Qw, Kw, Vtw, biasF, AO);
    gemm_bt<<<dim3(4, 93), dim3(256), 0, stream>>>(AO, WpT, d_in[4], MROWS,
        (__hip_bfloat16*)d_out, (float*)d_out, flagp);
}

// Round 9
// 215.835 us; speedup vs baseline: 1.0102x; 1.0102x over previous
//
#include <hip/hip_runtime.h>
#include <hip/hip_bf16.h>
#include <hip/hip_fp16.h>
#include <stdint.h>
#include <stddef.h>

typedef __attribute__((ext_vector_type(8))) short short8;
typedef __attribute__((ext_vector_type(4))) float f32x4;
typedef __attribute__((ext_vector_type(2))) float f32x2;
typedef unsigned short ushort_t;

#define NHEADS 16
#define HD 32
#define NQ 740
#define NB 16
#define MROWS (NB*NQ)       // 11840
#define CD 512
#define KDIM 512
#define VSTRIDE 768         // v^T row stride
#define NQT 48              // padded q-tile slots for bias
#define PTS 40              // P[q][key] stride in bf16 (32 keys + 8 pad)
#define QS2 0.2550400865f   // hd^-0.5 * log2(e)
#define LOG2E 1.4426950409f
#define NEG_BIG -43000.0f   // log2e-scaled mask; v_exp_f32 flushes to 0

static __device__ __forceinline__ void gld_lds16(const void* g, void* l) {
    __builtin_amdgcn_global_load_lds((const __attribute__((address_space(1))) void*)g,
                                     (__attribute__((address_space(3))) void*)l,
                                     16, 0, 0);
}

static __device__ __forceinline__ float ldf(const void* p, int i, int fl) {
    return fl ? ((const float*)p)[i] : (float)((const __hip_bfloat16*)p)[i];
}
static __device__ __forceinline__ ushort_t f2bf(float f) {
    __hip_bfloat16 h(f);
    return *reinterpret_cast<ushort_t*>(&h);
}
static __device__ __forceinline__ float fexp2(float x) {
#if __has_builtin(__builtin_amdgcn_exp2f)
    return __builtin_amdgcn_exp2f(x);
#else
    return exp2f(x);
#endif
}
// f32 -> e5m2 byte (RNE via fp16; e5m2 == fp16 top byte)
static __device__ __forceinline__ unsigned int f2e5(float f) {
    __half h = __float2half(f);
    unsigned short hb = *reinterpret_cast<unsigned short*>(&h);
    return (((unsigned int)hb + 0x7fu + ((hb >> 8) & 1u)) >> 8) & 0xffu;
}
// 4 packed e5m2 -> f32x4. gfx950: HW v_cvt_pk_f32_bf8 (OCP e5m2 == fp16 top byte)
#if __has_builtin(__builtin_amdgcn_cvt_pk_f32_bf8)
static __device__ __forceinline__ f32x4 bias4f8(unsigned int b) {
    f32x2 lo = __builtin_amdgcn_cvt_pk_f32_bf8((int)b, false);
    f32x2 hi = __builtin_amdgcn_cvt_pk_f32_bf8((int)b, true);
    f32x4 c;
    c[0] = lo[0]; c[1] = lo[1]; c[2] = hi[0]; c[3] = hi[1];
    return c;
}
#else
static __device__ __forceinline__ f32x4 bias4f8(unsigned int b) {
    f32x4 c;
    #pragma unroll
    for (int i = 0; i < 4; ++i) {
        union { unsigned short u; __half h; } cv;
        cv.u = (unsigned short)(((b >> (8 * i)) & 0xffu) << 8);
        c[i] = __half2float(cv.h);
    }
    return c;
}
#endif
// pack f32x4 -> 4 bf16 (RNE, packed HW cvt), single 8B LDS store
static __device__ __forceinline__ void pkstore(__hip_bfloat16* dst, f32x4 c) {
    __hip_bfloat162* d = (__hip_bfloat162*)dst;
    d[0] = __float22bfloat162_rn(make_float2(c[0], c[1]));
    d[1] = __float22bfloat162_rn(make_float2(c[2], c[3]));
}
static __device__ __forceinline__ uint2 pk4(float a, float b, float c, float d) {
    __hip_bfloat162 p01 = __float22bfloat162_rn(make_float2(a, b));
    __hip_bfloat162 p23 = __float22bfloat162_rn(make_float2(c, d));
    uint2 u;
    u.x = *reinterpret_cast<unsigned int*>(&p01);
    u.y = *reinterpret_cast<unsigned int*>(&p23);
    return u;
}

// ------------- dtype sniff: fp32 arrays have uniform low-16 mantissa bits ----
__global__ __launch_bounds__(64) void sniff_k(const unsigned int* __restrict__ w,
                                              int* __restrict__ flag) {
    int cnt = 0;
    for (int i = threadIdx.x; i < 1024; i += 64) {
        unsigned int e = (w[i] >> 7) & 0xFFu;
        cnt += (e > 135u) ? 1 : 0;
    }
    #pragma unroll
    for (int d = 1; d < 64; d <<= 1) cnt += __shfl_xor(cnt, d);
    if (threadIdx.x == 0) *flag = (cnt > 16) ? 1 : 0;
}

// ------- merged prep: convx | transpose Wqkv | transpose Wproj | biasF -------
// All bodies read only kernel inputs -> no cross-deps; one launch replaces 4.
#define PREP_CONV 1480
#define PREP_TA   768     // Wqkv transpose: 48 x 16
#define PREP_TB   256     // Wproj transpose: 16 x 16
#define PREP_BIAS 768     // biasF: 16*48
__global__ __launch_bounds__(256) void prep_k(
    const void* __restrict__ x, ushort4* __restrict__ Xb,
    const void* __restrict__ Wqkv, __hip_bfloat16* __restrict__ WqT,
    const void* __restrict__ Wproj, __hip_bfloat16* __restrict__ WpT,
    const void* __restrict__ btT, const void* __restrict__ btt,
    const void* __restrict__ ttab, const void* __restrict__ tgtab,
    const void* __restrict__ ttln, const void* __restrict__ tgln,
    unsigned int* __restrict__ biasF,
    const int* __restrict__ flag) {
    __shared__ __hip_bfloat16 tile[32][33];
    const int bid = blockIdx.x;
    const int tid = threadIdx.x;
    const int fl = *flag;

    if (bid < PREP_CONV) {
        const int n = MROWS * CD / 4;
        for (int i = bid * 256 + tid; i < n; i += PREP_CONV * 256) {
            if (fl) {
                float4 v = ((const float4*)x)[i];
                ushort4 o;
                o.x = f2bf(v.x); o.y = f2bf(v.y); o.z = f2bf(v.z); o.w = f2bf(v.w);
                Xb[i] = o;
            } else {
                Xb[i] = ((const ushort4*)x)[i];
            }
        }
        return;
    }
    if (bid < PREP_CONV + PREP_TA + PREP_TB) {
        const void* src; __hip_bfloat16* dst; int R, C, lb;
        if (bid < PREP_CONV + PREP_TA) {
            src = Wqkv; dst = WqT; R = 512; C = 1536; lb = bid - PREP_CONV;
        } else {
            src = Wproj; dst = WpT; R = 512; C = 512; lb = bid - PREP_CONV - PREP_TA;
        }
        int nbx = C / 32;
        int bx = (lb % nbx) * 32;
        int by = (lb / nbx) * 32;
        int tx = tid & 31, ty = tid >> 5;
        for (int r = ty; r < 32; r += 8)
            tile[r][tx] = __hip_bfloat16(ldf(src, (by + r) * C + bx + tx, fl));
        __syncthreads();
        for (int r = ty; r < 32; r += 8)
            dst[(size_t)(bx + r) * R + by + tx] = tile[tx][r];
        return;
    }
    // biasF: [blk=hh*48+qt][kb 48][lane 64] e5m2-packed uint
    const int blk = bid - (PREP_CONV + PREP_TA + PREP_TB);
    const int hh = blk / NQT;
    const int qt = blk - hh * NQT;
    for (int idx = tid; idx < 48 * 64; idx += 256) {
        const int lane = idx & 63;
        const int kb = idx >> 6;
        const int lr = lane & 15, kc = lane >> 4;
        int i = qt * 16 + lr; if (i > NQ - 1) i = NQ - 1;
        unsigned int pk = 0;
        #pragma unroll
        for (int r = 0; r < 4; ++r) {
            int c = kb * 16 + kc * 4 + r;
            float v;
            if (c >= NQ) {
                v = NEG_BIG;
            } else if (i < 256) {
                if (c < 256) {
                    int t = ((i >> 4) - (c >> 4) + 15) * 31 + ((i & 15) - (c & 15) + 15);
                    v = ldf(btt, t * 16 + hh, fl) * LOG2E;
                } else {
                    v = (ldf(tgtab, hh * 256 + i, fl) + ldf(tgln, hh * 484 + (c - 256), fl)) * LOG2E;
                }
            } else {
                int ii = i - 256;
                if (c < 256) {
                    v = (ldf(ttab, hh * 484 + ii, fl) + ldf(ttln, hh * 256 + c, fl)) * LOG2E;
                } else {
                    int jj = c - 256;
                    int a = ii / 22, b2 = ii - a * 22;
                    int a2 = jj / 22, b3 = jj - a2 * 22;
                    int t = (a - a2 + 21) * 43 + (b2 - b3 + 21);
                    v = ldf(btT, t * 16 + hh, fl) * LOG2E;
                }
            }
            pk |= f2e5(v) << (8 * r);
        }
        biasF[(size_t)blk * 48 * 64 + idx] = pk;
    }
}

// ------- qkv GEMM: 256x128 tile, 3-buf depth-2 (round-7 verified) + XCD swizzle
// A-panel (262KB) is shared by 12 consecutive tiles; default dispatch spreads
// them over 8 XCDs -> panel re-reads are L3 hits (~2x L2 latency) inside every
// per-step drain. Bijective chunked remap (71,71,71,71,70,70,70,70) gives each
// XCD a contiguous tile range: ~6 A-panels (1.5MB) + all B (1.5MB) = 3MB,
// L2-resident. K-loop VMEM queue is pure lambda-ordered gld_lds (no mixed
// VGPR loads) -> vmcnt(6) guarantee is insensitive to codegen perturbation.
__global__ __launch_bounds__(256) void gemm_qkv(
    const __hip_bfloat16* __restrict__ A,
    const __hip_bfloat16* __restrict__ Bt,
    const void* __restrict__ biasv,
    __hip_bfloat16* __restrict__ Qw,
    __hip_bfloat16* __restrict__ Kw,
    __hip_bfloat16* __restrict__ Vtw,
    const int* __restrict__ flag) {
    __shared__ __attribute__((aligned(16))) short sStage[3 * 12288];  // 72 KB
    const int tid = threadIdx.x;
    const int lane = tid & 63;
    const int wv = tid >> 6;
    const int lr = lane & 15, kc = lane >> 4;
    // XCD-chunked bijective remap over 564 tiles (dispatch heuristic: xcd=bid&7)
    const int lin = blockIdx.x;
    const int xcd = lin & 7;
    const int idx = lin >> 3;
    const int tile = (xcd < 4 ? xcd * 71 : 284 + (xcd - 4) * 70) + idx;
    const int m0 = (tile / 12) * 256;
    const int n0 = (tile % 12) * 128;
    const int fl = *flag;
    const int M = MROWS;

    auto stage = [&](int s) {
        char* bb = (char*)sStage + (s % 3) * 24576;
        const int k0 = s * 32;
        #pragma unroll
        for (int it = 0; it < 6; ++it) {
            int idx2 = it * 256 + tid;
            if (idx2 < 1024) {
                int r = idx2 >> 2, c = idx2 & 3;
                int gr = m0 + r; if (gr > M - 1) gr = M - 1;
                gld_lds16(A + (size_t)gr * KDIM + k0 + c * 8, bb + idx2 * 16);
            } else {
                int u = idx2 - 1024;
                int r = u >> 2, c = u & 3;
                gld_lds16(Bt + (size_t)(n0 + r) * KDIM + k0 + c * 8, bb + 16384 + u * 16);
            }
        }
    };

    f32x4 acc[4][8] = {};
    stage(0);
    stage(1);

    for (int ks = 0; ks < 16; ++ks) {
        asm volatile("" ::: "memory");
        if (ks < 15) __builtin_amdgcn_s_waitcnt(0x0076);  // vmcnt(6) lgkm(0)
        else         __builtin_amdgcn_s_waitcnt(0x0070);
        __builtin_amdgcn_s_barrier();
        asm volatile("" ::: "memory");
        if (ks + 2 < 16) stage(ks + 2);

        const char* bb = (const char*)sStage + (ks % 3) * 24576;
        const short* cA = (const short*)bb;
        const short* cB = (const short*)(bb + 16384);
        short8 af[4], bfr[8];
        #pragma unroll
        for (int t = 0; t < 4; ++t)
            af[t] = *(const short8*)&cA[(wv * 64 + t * 16 + lr) * 32 + kc * 8];
        #pragma unroll
        for (int t = 0; t < 8; ++t)
            bfr[t] = *(const short8*)&cB[(t * 16 + lr) * 32 + kc * 8];
        #pragma unroll
        for (int i = 0; i < 4; ++i)
            #pragma unroll
            for (int j = 0; j < 8; ++j)
                acc[i][j] = __builtin_amdgcn_mfma_f32_16x16x32_bf16(af[i], bfr[j], acc[i][j], 0, 0, 0);
    }

    // ---- epilogue: LDS repack (buffer 1) -> coalesced global stores ----
    const int s = n0 >> 9;
    short* Tw = (short*)((char*)sStage + 24576) + wv * 2560;
    const int gmr = m0 + wv * 64 + lane;
    int gmrc = gmr < M ? gmr : M - 1;
    int bq = gmrc / NQ;
    int nnq = gmrc - bq * NQ;
    const int gmv = m0 + wv * 64 + (lane & 15) * 4;
    int gmvc = gmv < M ? gmv : M - 1;
    int bv2 = gmvc / NQ;
    int nnv = gmvc - bv2 * NQ;

    #pragma unroll
    for (int t = 0; t < 4; ++t) {
        const int hh = ((n0 >> 5) + t) & 15;
        float bva = ldf(biasv, n0 + t * 32 + lr, fl);
        float bvb = ldf(biasv, n0 + t * 32 + 16 + lr, fl);
        asm volatile("" ::: "memory");
        if (s == 2) {
            #pragma unroll
            for (int i = 0; i < 4; ++i) {
                int nl = i * 16 + kc * 4;
                uint2 ua = pk4(acc[i][2*t][0] + bva, acc[i][2*t][1] + bva,
                               acc[i][2*t][2] + bva, acc[i][2*t][3] + bva);
                uint2 ub = pk4(acc[i][2*t+1][0] + bvb, acc[i][2*t+1][1] + bvb,
                               acc[i][2*t+1][2] + bvb, acc[i][2*t+1][3] + bvb);
                *(uint2*)(void*)&Tw[lr * 72 + nl]        = ua;
                *(uint2*)(void*)&Tw[(16 + lr) * 72 + nl] = ub;
            }
        } else {
            float sc = (s == 0) ? QS2 : 1.0f;
            #pragma unroll
            for (int i = 0; i < 4; ++i)
                #pragma unroll
                for (int r = 0; r < 4; ++r) {
                    int nl = i * 16 + kc * 4 + r;
                    Tw[nl * 40 + lr]      = (short)f2bf((acc[i][2*t][r]   + bva) * sc);
                    Tw[nl * 40 + 16 + lr] = (short)f2bf((acc[i][2*t+1][r] + bvb) * sc);
                }
        }
        asm volatile("" ::: "memory");
        __builtin_amdgcn_s_waitcnt(0xc07f);
        asm volatile("" ::: "memory");
        if (s == 2) {
            if (gmv < M) {
                size_t bh = (size_t)(bv2 * 16 + hh);
                #pragma unroll
                for (int i2 = 0; i2 < 8; ++i2) {
                    int d = (lane >> 4) + i2 * 4;
                    uint2 u = *(const uint2*)(const void*)&Tw[d * 72 + (lane & 15) * 4];
                    *(uint2*)(void*)(Vtw + (bh * HD + d) * VSTRIDE + nnv) = u;
                }
            }
        } else {
            if (gmr < M) {
                size_t bh = (size_t)(bq * 16 + hh);
                __hip_bfloat16* dst = (s == 0 ? Qw : Kw) + (bh * NQ + nnq) * HD;
                #pragma unroll
                for (int c = 0; c < 4; ++c) {
                    short8 u = *(const short8*)(const void*)&Tw[lane * 40 + c * 8];
                    *(short8*)(void*)(dst + c * 8) = u;
                }
            }
        }
        asm volatile("" ::: "memory");
        __builtin_amdgcn_s_waitcnt(0xc07f);
        asm volatile("" ::: "memory");
    }
}

// ----- proj GEMM: 128x128, PIPELINED K-loop (3-buf, depth-2): Out=A@Bt^T+bias
__global__ __launch_bounds__(256) void gemm_bt(
    const __hip_bfloat16* __restrict__ A,
    const __hip_bfloat16* __restrict__ Bt,
    const void* __restrict__ biasv,
    int M,
    __hip_bfloat16* __restrict__ Out,
    float* __restrict__ OutF,
    const int* __restrict__ flag) {
    __shared__ __attribute__((aligned(16))) short sStage[3 * 8192];   // 48 KB
    const int tid = threadIdx.x;
    const int lane = tid & 63;
    const int wv = tid >> 6;
    const int wr = wv >> 1, wc = wv & 1;
    const int lr = lane & 15, kc = lane >> 4;
    const int m0 = blockIdx.y * 128;
    const int n0 = blockIdx.x * 128;
    const int fl = *flag;

    auto stage = [&](int s) {
        char* bb = (char*)sStage + (s % 3) * 16384;
        const int k0 = s * 32;
        #pragma unroll
        for (int it = 0; it < 2; ++it) {
            int idx = it * 256 + tid;
            int r = idx >> 2;
            int c = idx & 3;
            int gr = m0 + r; if (gr > M - 1) gr = M - 1;
            gld_lds16(A + (size_t)gr * KDIM + k0 + c * 8, bb + idx * 16);
            gld_lds16(Bt + (size_t)(n0 + r) * KDIM + k0 + c * 8, bb + 8192 + idx * 16);
        }
    };

    f32x4 acc[4][4] = {};
    stage(0);
    stage(1);

    for (int ks = 0; ks < 16; ++ks) {
        asm volatile("" ::: "memory");
        if (ks < 15) __builtin_amdgcn_s_waitcnt(0x0074);  // vmcnt(4) lgkm(0)
        else         __builtin_amdgcn_s_waitcnt(0x0070);
        __builtin_amdgcn_s_barrier();
        asm volatile("" ::: "memory");
        if (ks + 2 < 16) stage(ks + 2);

        const char* bb = (const char*)sStage + (ks % 3) * 16384;
        const short* cA = (const short*)bb;
        const short* cB = (const short*)(bb + 8192);
        short8 af[4], bfr[4];
        #pragma unroll
        for (int t = 0; t < 4; ++t)
            af[t] = *(const short8*)&cA[(wr * 64 + t * 16 + lr) * 32 + kc * 8];
        #pragma unroll
        for (int t = 0; t < 4; ++t)
            bfr[t] = *(const short8*)&cB[(wc * 64 + t * 16 + lr) * 32 + kc * 8];
        #pragma unroll
        for (int i = 0; i < 4; ++i)
            #pragma unroll
            for (int j = 0; j < 4; ++j)
                acc[i][j] = __builtin_amdgcn_mfma_f32_16x16x32_bf16(af[i], bfr[j], acc[i][j], 0, 0, 0);
    }

    #pragma unroll
    for (int i = 0; i < 4; ++i) {
        #pragma unroll
        for (int j = 0; j < 4; ++j) {
            int gn = n0 + wc * 64 + j * 16 + lr;
            float bv = ldf(biasv, gn, fl);
            #pragma unroll
            for (int r = 0; r < 4; ++r) {
                int gm = m0 + wr * 64 + i * 16 + kc * 4 + r;
                if (gm < M) {
                    float v = acc[i][j][r] + bv;
                    if (fl) OutF[(size_t)gm * CD + gn] = v;
                    else    Out[(size_t)gm * CD + gn] = __hip_bfloat16(v);
                }
            }
        }
    }
}

// ---- fused attention v14: v9 sync skeleton, 64 q-rows per wave (VERIFIED) --
__global__ __launch_bounds__(256, 3) void attn_k(
    const __hip_bfloat16* __restrict__ Qw,
    const __hip_bfloat16* __restrict__ Kw,
    const __hip_bfloat16* __restrict__ Vtw,
    const unsigned int* __restrict__ biasF,
    __hip_bfloat16* __restrict__ AO) {
    __shared__ __attribute__((aligned(16))) short sStage[3 * 2048];        // 12 KB
    __shared__ __attribute__((aligned(16))) __hip_bfloat16 Pt[4][64 * PTS]; // 20.5 KB

    const int tid = threadIdx.x;
    const int wv = tid >> 6;
    const int p = blockIdx.x * 4 + wv;       // 0..11: 64 q-rows per wave
    const int bh = blockIdx.y;               // b*16 + h
    const int hh = bh & 15;
    const int b = bh >> 4;
    const int q0 = p * 64;
    const int lane = tid & 63;
    const int lr = lane & 15, kc = lane >> 4;

    const __hip_bfloat16* Qb = Qw + (size_t)bh * NQ * HD;
    const __hip_bfloat16* Kb = Kw + (size_t)bh * NQ * HD;
    const __hip_bfloat16* Vb = Vtw + (size_t)bh * HD * VSTRIDE;
    __hip_bfloat16* Pw = &Pt[wv][0];

    short8 qfA = *(const short8*)(const void*)(Qb + (q0 + lr) * HD + kc * 8);
    short8 qfB = *(const short8*)(const void*)(Qb + (q0 + 16 + lr) * HD + kc * 8);
    short8 qfC = *(const short8*)(const void*)(Qb + (q0 + 32 + lr) * HD + kc * 8);
    short8 qfD = *(const short8*)(const void*)(Qb + (q0 + 48 + lr) * HD + kc * 8);

    short8 onesf;
    {
        short s1 = (lr == 0) ? (short)0x3F80 : (short)0;
        #pragma unroll
        for (int j = 0; j < 8; ++j) onesf[j] = s1;
    }

    // bias slices for the wave's 4 q-16-tiles: 4p+0..4p+3 (<= 47 < NQT)
    const unsigned int* bt0 = biasF + (size_t)(hh * NQT + 4 * p) * 48 * 64 + lane;
    const unsigned int* bt1 = bt0 + 48 * 64;
    const unsigned int* bt2 = bt0 + 2 * 48 * 64;
    const unsigned int* bt3 = bt0 + 3 * 48 * 64;

    unsigned int brA0[2], brA1[2], brB0[2], brB1[2];
    unsigned int brC0[2], brC1[2], brD0[2], brD1[2];
    brA0[0] = bt0[0];  brA1[0] = bt0[64];
    brB0[0] = bt1[0];  brB1[0] = bt1[64];
    brC0[0] = bt2[0];  brC1[0] = bt2[64];
    brD0[0] = bt3[0];  brD1[0] = bt3[64];

    // staging: [unit 4][row 32] blocks (transposed lane mapping). K: lanes
    // 0..127 (row=l&31, unit=l>>5); V: lanes 128..255 (d=u&31, unit=u>>5).
    // IDENTICAL to v9 (verified).
    {
        const void* src;
        if (tid < 128) src = Kb + (tid & 31) * HD + (tid >> 5) * 8;
        else { int u = tid - 128; src = Vb + (u & 31) * VSTRIDE + ((u >> 5) & 3) * 8; }
        gld_lds16(src, (char*)sStage + tid * 16);
    }
    asm volatile("" ::: "memory");

    f32x4 oa0 = {}, ob0 = {}, ol0 = {};
    f32x4 oa1 = {}, ob1 = {}, ol1 = {};
    f32x4 oa2 = {}, ob2 = {}, ol2 = {};
    f32x4 oa3 = {}, ob3 = {}, ol3 = {};

    #pragma unroll
    for (int ks = 0; ks < 24; ++ks) {
        const int cur = ks & 1, nxt = cur ^ 1;
        if (ks < 23) {
            brA0[nxt] = bt0[(2 * ks + 2) * 64];
            brA1[nxt] = bt0[(2 * ks + 3) * 64];
            brB0[nxt] = bt1[(2 * ks + 2) * 64];
            brB1[nxt] = bt1[(2 * ks + 3) * 64];
            brC0[nxt] = bt2[(2 * ks + 2) * 64];
            brC1[nxt] = bt2[(2 * ks + 3) * 64];
            brD0[nxt] = bt3[(2 * ks + 2) * 64];
            brD1[nxt] = bt3[(2 * ks + 3) * 64];
            const int k0n = (ks + 1) * 32;
            const int nb = ((ks + 1) % 3) * 4096;
            const void* src;
            if (tid < 128) src = Kb + (k0n + (tid & 31)) * HD + (tid >> 5) * 8;
            else { int u = tid - 128; src = Vb + (u & 31) * VSTRIDE + k0n + ((u >> 5) & 3) * 8; }
            gld_lds16(src, (char*)sStage + nb + tid * 16);
        }
        asm volatile("" ::: "memory");
        if (ks < 23) __builtin_amdgcn_s_waitcnt(0x0F79);   // vmcnt(9): bias(ks+1)8+stage(ks+1)1
        else         __builtin_amdgcn_s_waitcnt(0x0F70);   // vmcnt(0)
        __builtin_amdgcn_s_barrier();
        asm volatile("" ::: "memory");

        const short* sK = (const short*)((const char*)sStage + (ks % 3) * 4096);
        const short* sV = sK + 1024;
        // [unit][row]: addr = kc*256 + row*8 shorts -> 2-way banks (free)
        short8 kf0 = *(const short8*)&sK[kc * 256 + lr * 8];
        short8 kf1 = *(const short8*)&sK[kc * 256 + (16 + lr) * 8];
        short8 vf0 = *(const short8*)&sV[kc * 256 + lr * 8];
        short8 vf1 = *(const short8*)&sV[kc * 256 + (16 + lr) * 8];

        // ---- q-set 1 (tiles 4p, 4p+1) ----
        {
            f32x4 c0 = bias4f8(brA0[cur]);
            f32x4 c1 = bias4f8(brA1[cur]);
            f32x4 c2 = bias4f8(brB0[cur]);
            f32x4 c3 = bias4f8(brB1[cur]);

            c0 = __builtin_amdgcn_mfma_f32_16x16x32_bf16(kf0, qfA, c0, 0, 0, 0);
            c1 = __builtin_amdgcn_mfma_f32_16x16x32_bf16(kf1, qfA, c1, 0, 0, 0);
            c2 = __builtin_amdgcn_mfma_f32_16x16x32_bf16(kf0, qfB, c2, 0, 0, 0);
            c3 = __builtin_amdgcn_mfma_f32_16x16x32_bf16(kf1, qfB, c3, 0, 0, 0);

            #pragma unroll
            for (int r = 0; r < 4; ++r) {
                c0[r] = fexp2(c0[r]); c1[r] = fexp2(c1[r]);
                c2[r] = fexp2(c2[r]); c3[r] = fexp2(c3[r]);
            }
            pkstore(Pw + lr * PTS + kc * 4, c0);
            pkstore(Pw + lr * PTS + 16 + kc * 4, c1);
            pkstore(Pw + (16 + lr) * PTS + kc * 4, c2);
            pkstore(Pw + (16 + lr) * PTS + 16 + kc * 4, c3);
        }
        // ---- q-set 2 (tiles 4p+2, 4p+3) ----
        {
            f32x4 c0 = bias4f8(brC0[cur]);
            f32x4 c1 = bias4f8(brC1[cur]);
            f32x4 c2 = bias4f8(brD0[cur]);
            f32x4 c3 = bias4f8(brD1[cur]);

            c0 = __builtin_amdgcn_mfma_f32_16x16x32_bf16(kf0, qfC, c0, 0, 0, 0);
            c1 = __builtin_amdgcn_mfma_f32_16x16x32_bf16(kf1, qfC, c1, 0, 0, 0);
            c2 = __builtin_amdgcn_mfma_f32_16x16x32_bf16(kf0, qfD, c2, 0, 0, 0);
            c3 = __builtin_amdgcn_mfma_f32_16x16x32_bf16(kf1, qfD, c3, 0, 0, 0);

            #pragma unroll
            for (int r = 0; r < 4; ++r) {
                c0[r] = fexp2(c0[r]); c1[r] = fexp2(c1[r]);
                c2[r] = fexp2(c2[r]); c3[r] = fexp2(c3[r]);
            }
            pkstore(Pw + (32 + lr) * PTS + kc * 4, c0);
            pkstore(Pw + (32 + lr) * PTS + 16 + kc * 4, c1);
            pkstore(Pw + (48 + lr) * PTS + kc * 4, c2);
            pkstore(Pw + (48 + lr) * PTS + 16 + kc * 4, c3);
        }
        asm volatile("" ::: "memory");
        __builtin_amdgcn_s_waitcnt(0xc07f);   // lgkmcnt(0)
        asm volatile("" ::: "memory");

        short8 pfA = *(const short8*)(const void*)(Pw + lr * PTS + kc * 8);
        short8 pfB = *(const short8*)(const void*)(Pw + (16 + lr) * PTS + kc * 8);
        short8 pfC = *(const short8*)(const void*)(Pw + (32 + lr) * PTS + kc * 8);
        short8 pfD = *(const short8*)(const void*)(Pw + (48 + lr) * PTS + kc * 8);

        oa0 = __builtin_amdgcn_mfma_f32_16x16x32_bf16(pfA, vf0, oa0, 0, 0, 0);
        ob0 = __builtin_amdgcn_mfma_f32_16x16x32_bf16(pfA, vf1, ob0, 0, 0, 0);
        ol0 = __builtin_amdgcn_mfma_f32_16x16x32_bf16(pfA, onesf, ol0, 0, 0, 0);
        oa1 = __builtin_amdgcn_mfma_f32_16x16x32_bf16(pfB, vf0, oa1, 0, 0, 0);
        ob1 = __builtin_amdgcn_mfma_f32_16x16x32_bf16(pfB, vf1, ob1, 0, 0, 0);
        ol1 = __builtin_amdgcn_mfma_f32_16x16x32_bf16(pfB, onesf, ol1, 0, 0, 0);
        oa2 = __builtin_amdgcn_mfma_f32_16x16x32_bf16(pfC, vf0, oa2, 0, 0, 0);
        ob2 = __builtin_amdgcn_mfma_f32_16x16x32_bf16(pfC, vf1, ob2, 0, 0, 0);
        ol2 = __builtin_amdgcn_mfma_f32_16x16x32_bf16(pfC, onesf, ol2, 0, 0, 0);
        oa3 = __builtin_amdgcn_mfma_f32_16x16x32_bf16(pfD, vf0, oa3, 0, 0, 0);
        ob3 = __builtin_amdgcn_mfma_f32_16x16x32_bf16(pfD, vf1, ob3, 0, 0, 0);
        ol3 = __builtin_amdgcn_mfma_f32_16x16x32_bf16(pfD, onesf, ol3, 0, 0, 0);
    }

    #pragma unroll
    for (int r = 0; r < 4; ++r) {
        int row = kc * 4 + r;
        float lA = __shfl(ol0[r], lane & 48);
        float lB = __shfl(ol1[r], lane & 48);
        float lC = __shfl(ol2[r], lane & 48);
        float lD = __shfl(ol3[r], lane & 48);
        float liA = 1.0f / lA, liB = 1.0f / lB;
        float liC = 1.0f / lC, liD = 1.0f / lD;
        int orA = q0 + row, orB = q0 + 16 + row;
        int orC = q0 + 32 + row, orD = q0 + 48 + row;
        if (orA < NQ) {
            size_t base = ((size_t)b * NQ + orA) * CD + hh * HD;
            AO[base + lr]      = __hip_bfloat16(oa0[r] * liA);
            AO[base + 16 + lr] = __hip_bfloat16(ob0[r] * liA);
        }
        if (orB < NQ) {
            size_t base = ((size_t)b * NQ + orB) * CD + hh * HD;
            AO[base + lr]      = __hip_bfloat16(oa1[r] * liB);
            AO[base + 16 + lr] = __hip_bfloat16(ob1[r] * liB);
        }
        if (orC < NQ) {
            size_t base = ((size_t)b * NQ + orC) * CD + hh * HD;
            AO[base + lr]      = __hip_bfloat16(oa2[r] * liC);
            AO[base + 16 + lr] = __hip_bfloat16(ob2[r] * liC);
        }
        if (orD < NQ) {
            size_t base = ((size_t)b * NQ + orD) * CD + hh * HD;
            AO[base + lr]      = __hip_bfloat16(oa3[r] * liD);
            AO[base + 16 + lr] = __hip_bfloat16(ob3[r] * liD);
        }
    }
}

extern "C" void kernel_launch(void* const* d_in, const int* in_sizes, int n_in,
                              void* d_out, int out_size, void* d_ws, size_t ws_size,
                              hipStream_t stream) {
    char* ws = (char*)d_ws;
    size_t off = 0;
    auto carve = [&](size_t bytes) {
        char* p = ws + off;
        off += (bytes + 255) & ~(size_t)255;
        return p;
    };
    int* flagp = (int*)carve(256);
    __hip_bfloat16* Qw    = (__hip_bfloat16*)carve((size_t)256 * NQ * HD * 2);
    __hip_bfloat16* Kw    = (__hip_bfloat16*)carve((size_t)256 * NQ * HD * 2);
    __hip_bfloat16* Vtw   = (__hip_bfloat16*)carve((size_t)256 * HD * VSTRIDE * 2);
    __hip_bfloat16* WqT   = (__hip_bfloat16*)carve((size_t)1536 * 512 * 2);
    __hip_bfloat16* WpT   = (__hip_bfloat16*)carve((size_t)512 * 512 * 2);
    unsigned int*   biasF = (unsigned int*)carve((size_t)16 * NQT * 48 * 64 * 4);
    __hip_bfloat16* Xb    = (__hip_bfloat16*)carve((size_t)MROWS * CD * 2);
    __hip_bfloat16* AO    = Xb;   // attn output overwrites x-staging (dead after qkv gemm)
    (void)ws_size; (void)in_sizes; (void)n_in; (void)out_size;

    sniff_k<<<dim3(1), dim3(64), 0, stream>>>((const unsigned int*)d_in[1], flagp);
    prep_k<<<dim3(PREP_CONV + PREP_TA + PREP_TB + PREP_BIAS), dim3(256), 0, stream>>>(
        d_in[0], (ushort4*)Xb, d_in[1], WqT, d_in[3], WpT,
        d_in[5], d_in[6], d_in[7], d_in[8], d_in[9], d_in[10], biasF, flagp);
    gemm_qkv<<<dim3(564), dim3(256), 0, stream>>>(Xb, WqT, d_in[2],
        Qw, Kw, Vtw, flagp);
    attn_k<<<dim3(3, 256), dim3(256), 0, stream>>>(Qw, Kw, Vtw, biasF, AO);
    gemm_bt<<<dim3(4, 93), dim3(256), 0, stream>>>(AO, WpT, d_in[4], MROWS,
        (__hip_bfloat16*)d_out, (float*)d_out, flagp);
}

// Round 10
// 205.366 us; speedup vs baseline: 1.0617x; 1.0510x over previous
//
#include <hip/hip_runtime.h>
#include <hip/hip_bf16.h>
#include <hip/hip_fp16.h>
#include <stdint.h>
#include <stddef.h>

typedef __attribute__((ext_vector_type(8))) short short8;
typedef __attribute__((ext_vector_type(4))) float f32x4;
typedef __attribute__((ext_vector_type(2))) float f32x2;
typedef unsigned short ushort_t;

#define NHEADS 16
#define HD 32
#define NQ 740
#define NB 16
#define MROWS (NB*NQ)       // 11840
#define CD 512
#define KDIM 512
#define VSTRIDE 768         // v^T row stride
#define NQT 48              // padded q-tile slots for bias
#define PTS 40              // P[q][key] stride in bf16 (32 keys + 8 pad)
#define QS2 0.2550400865f   // hd^-0.5 * log2(e)
#define LOG2E 1.4426950409f
#define NEG_BIG -43000.0f   // log2e-scaled mask; v_exp_f32 flushes to 0

static __device__ __forceinline__ void gld_lds16(const void* g, void* l) {
    __builtin_amdgcn_global_load_lds((const __attribute__((address_space(1))) void*)g,
                                     (__attribute__((address_space(3))) void*)l,
                                     16, 0, 0);
}

static __device__ __forceinline__ float ldf(const void* p, int i, int fl) {
    return fl ? ((const float*)p)[i] : (float)((const __hip_bfloat16*)p)[i];
}
static __device__ __forceinline__ ushort_t f2bf(float f) {
    __hip_bfloat16 h(f);
    return *reinterpret_cast<ushort_t*>(&h);
}
static __device__ __forceinline__ float fexp2(float x) {
#if __has_builtin(__builtin_amdgcn_exp2f)
    return __builtin_amdgcn_exp2f(x);
#else
    return exp2f(x);
#endif
}
// f32 -> e5m2 byte (RNE via fp16; e5m2 == fp16 top byte)
static __device__ __forceinline__ unsigned int f2e5(float f) {
    __half h = __float2half(f);
    unsigned short hb = *reinterpret_cast<unsigned short*>(&h);
    return (((unsigned int)hb + 0x7fu + ((hb >> 8) & 1u)) >> 8) & 0xffu;
}
// 4 packed e5m2 -> f32x4. gfx950: HW v_cvt_pk_f32_bf8 (OCP e5m2 == fp16 top byte)
#if __has_builtin(__builtin_amdgcn_cvt_pk_f32_bf8)
static __device__ __forceinline__ f32x4 bias4f8(unsigned int b) {
    f32x2 lo = __builtin_amdgcn_cvt_pk_f32_bf8((int)b, false);
    f32x2 hi = __builtin_amdgcn_cvt_pk_f32_bf8((int)b, true);
    f32x4 c;
    c[0] = lo[0]; c[1] = lo[1]; c[2] = hi[0]; c[3] = hi[1];
    return c;
}
#else
static __device__ __forceinline__ f32x4 bias4f8(unsigned int b) {
    f32x4 c;
    #pragma unroll
    for (int i = 0; i < 4; ++i) {
        union { unsigned short u; __half h; } cv;
        cv.u = (unsigned short)(((b >> (8 * i)) & 0xffu) << 8);
        c[i] = __half2float(cv.h);
    }
    return c;
}
#endif
// pack f32x4 -> 4 bf16 (RNE, packed HW cvt), single 8B LDS store
static __device__ __forceinline__ void pkstore(__hip_bfloat16* dst, f32x4 c) {
    __hip_bfloat162* d = (__hip_bfloat162*)dst;
    d[0] = __float22bfloat162_rn(make_float2(c[0], c[1]));
    d[1] = __float22bfloat162_rn(make_float2(c[2], c[3]));
}
static __device__ __forceinline__ uint2 pk4(float a, float b, float c, float d) {
    __hip_bfloat162 p01 = __float22bfloat162_rn(make_float2(a, b));
    __hip_bfloat162 p23 = __float22bfloat162_rn(make_float2(c, d));
    uint2 u;
    u.x = *reinterpret_cast<unsigned int*>(&p01);
    u.y = *reinterpret_cast<unsigned int*>(&p23);
    return u;
}

// ------- merged prep: sniff | convx | transpose Wqkv/Wproj | biasF ----------
// Round-10: sniff_k folded in (every block recomputes the identical flag from
// the same 1024 words -> deterministic; bid 0 publishes for downstream
// kernels; same-stream kernel boundary guarantees visibility). Bias-build
// split 4x (768 -> 3072 blocks, 12-kb quarter each; per-output math and
// addresses byte-identical) to hide the scattered-gather latency with TLP.
#define PREP_CONV 1480
#define PREP_TA   768     // Wqkv transpose: 48 x 16
#define PREP_TB   256     // Wproj transpose: 16 x 16
#define PREP_BIAS 3072    // biasF: 16*48*4 quarters
__global__ __launch_bounds__(256) void prep_k(
    const void* __restrict__ x, ushort4* __restrict__ Xb,
    const void* __restrict__ Wqkv, __hip_bfloat16* __restrict__ WqT,
    const void* __restrict__ Wproj, __hip_bfloat16* __restrict__ WpT,
    const void* __restrict__ btT, const void* __restrict__ btt,
    const void* __restrict__ ttab, const void* __restrict__ tgtab,
    const void* __restrict__ ttln, const void* __restrict__ tgln,
    unsigned int* __restrict__ biasF,
    int* __restrict__ flagp) {
    __shared__ __hip_bfloat16 tile[32][33];
    __shared__ int redf[4];
    const int bid = blockIdx.x;
    const int tid = threadIdx.x;

    // ---- folded dtype sniff: fp32 arrays have uniform high exponents ----
    int cnt = 0;
    {
        const unsigned int* wq = (const unsigned int*)Wqkv;
        for (int i = tid; i < 1024; i += 256) {
            unsigned int e = (wq[i] >> 7) & 0xFFu;
            cnt += (e > 135u) ? 1 : 0;
        }
        #pragma unroll
        for (int d = 1; d < 64; d <<= 1) cnt += __shfl_xor(cnt, d);
        if ((tid & 63) == 0) redf[tid >> 6] = cnt;
        __syncthreads();
        cnt = redf[0] + redf[1] + redf[2] + redf[3];
    }
    const int fl = (cnt > 16) ? 1 : 0;
    if (bid == 0 && tid == 0) *flagp = fl;

    if (bid < PREP_CONV) {
        const int n = MROWS * CD / 4;
        for (int i = bid * 256 + tid; i < n; i += PREP_CONV * 256) {
            if (fl) {
                float4 v = ((const float4*)x)[i];
                ushort4 o;
                o.x = f2bf(v.x); o.y = f2bf(v.y); o.z = f2bf(v.z); o.w = f2bf(v.w);
                Xb[i] = o;
            } else {
                Xb[i] = ((const ushort4*)x)[i];
            }
        }
        return;
    }
    if (bid < PREP_CONV + PREP_TA + PREP_TB) {
        const void* src; __hip_bfloat16* dst; int R, C, lb;
        if (bid < PREP_CONV + PREP_TA) {
            src = Wqkv; dst = WqT; R = 512; C = 1536; lb = bid - PREP_CONV;
        } else {
            src = Wproj; dst = WpT; R = 512; C = 512; lb = bid - PREP_CONV - PREP_TA;
        }
        int nbx = C / 32;
        int bx = (lb % nbx) * 32;
        int by = (lb / nbx) * 32;
        int tx = tid & 31, ty = tid >> 5;
        for (int r = ty; r < 32; r += 8)
            tile[r][tx] = __hip_bfloat16(ldf(src, (by + r) * C + bx + tx, fl));
        __syncthreads();
        for (int r = ty; r < 32; r += 8)
            dst[(size_t)(bx + r) * R + by + tx] = tile[tx][r];
        return;
    }
    // biasF: [blk=hh*48+qt][kb 48][lane 64] e5m2-packed uint; 12-kb quarter/block
    const int blk2 = bid - (PREP_CONV + PREP_TA + PREP_TB);
    const int hh = blk2 / 192;
    const int rem = blk2 - hh * 192;
    const int qt = rem >> 2;
    const int quarter = rem & 3;
    const size_t obase = (size_t)(hh * NQT + qt) * 48 * 64;
    for (int idx = tid; idx < 12 * 64; idx += 256) {
        const int lane = idx & 63;
        const int kb = quarter * 12 + (idx >> 6);
        const int lr = lane & 15, kc = lane >> 4;
        int i = qt * 16 + lr; if (i > NQ - 1) i = NQ - 1;
        unsigned int pk = 0;
        #pragma unroll
        for (int r = 0; r < 4; ++r) {
            int c = kb * 16 + kc * 4 + r;
            float v;
            if (c >= NQ) {
                v = NEG_BIG;
            } else if (i < 256) {
                if (c < 256) {
                    int t = ((i >> 4) - (c >> 4) + 15) * 31 + ((i & 15) - (c & 15) + 15);
                    v = ldf(btt, t * 16 + hh, fl) * LOG2E;
                } else {
                    v = (ldf(tgtab, hh * 256 + i, fl) + ldf(tgln, hh * 484 + (c - 256), fl)) * LOG2E;
                }
            } else {
                int ii = i - 256;
                if (c < 256) {
                    v = (ldf(ttab, hh * 484 + ii, fl) + ldf(ttln, hh * 256 + c, fl)) * LOG2E;
                } else {
                    int jj = c - 256;
                    int a = ii / 22, b2 = ii - a * 22;
                    int a2 = jj / 22, b3 = jj - a2 * 22;
                    int t = (a - a2 + 21) * 43 + (b2 - b3 + 21);
                    v = ldf(btT, t * 16 + hh, fl) * LOG2E;
                }
            }
            pk |= f2e5(v) << (8 * r);
        }
        biasF[obase + kb * 64 + lane] = pk;
    }
}

// ------- qkv GEMM: 256x128 tile, 3-buf depth-2 + XCD-chunked remap ----------
// Remap (71,71,71,71,70,70,70,70) keeps each A-panel's 12 consumer tiles on
// one XCD: FETCH 51->17MB (round-9 verified). K-loop VMEM queue is pure
// lambda-ordered gld_lds -> vmcnt(6) guarantee insensitive to codegen.
__global__ __launch_bounds__(256) void gemm_qkv(
    const __hip_bfloat16* __restrict__ A,
    const __hip_bfloat16* __restrict__ Bt,
    const void* __restrict__ biasv,
    __hip_bfloat16* __restrict__ Qw,
    __hip_bfloat16* __restrict__ Kw,
    __hip_bfloat16* __restrict__ Vtw,
    const int* __restrict__ flag) {
    __shared__ __attribute__((aligned(16))) short sStage[3 * 12288];  // 72 KB
    const int tid = threadIdx.x;
    const int lane = tid & 63;
    const int wv = tid >> 6;
    const int lr = lane & 15, kc = lane >> 4;
    // XCD-chunked bijective remap over 564 tiles (dispatch heuristic: xcd=bid&7)
    const int lin = blockIdx.x;
    const int xcd = lin & 7;
    const int idx = lin >> 3;
    const int tile = (xcd < 4 ? xcd * 71 : 284 + (xcd - 4) * 70) + idx;
    const int m0 = (tile / 12) * 256;
    const int n0 = (tile % 12) * 128;
    const int fl = *flag;
    const int M = MROWS;

    auto stage = [&](int s) {
        char* bb = (char*)sStage + (s % 3) * 24576;
        const int k0 = s * 32;
        #pragma unroll
        for (int it = 0; it < 6; ++it) {
            int idx2 = it * 256 + tid;
            if (idx2 < 1024) {
                int r = idx2 >> 2, c = idx2 & 3;
                int gr = m0 + r; if (gr > M - 1) gr = M - 1;
                gld_lds16(A + (size_t)gr * KDIM + k0 + c * 8, bb + idx2 * 16);
            } else {
                int u = idx2 - 1024;
                int r = u >> 2, c = u & 3;
                gld_lds16(Bt + (size_t)(n0 + r) * KDIM + k0 + c * 8, bb + 16384 + u * 16);
            }
        }
    };

    f32x4 acc[4][8] = {};
    stage(0);
    stage(1);

    for (int ks = 0; ks < 16; ++ks) {
        asm volatile("" ::: "memory");
        if (ks < 15) __builtin_amdgcn_s_waitcnt(0x0076);  // vmcnt(6) lgkm(0)
        else         __builtin_amdgcn_s_waitcnt(0x0070);
        __builtin_amdgcn_s_barrier();
        asm volatile("" ::: "memory");
        if (ks + 2 < 16) stage(ks + 2);

        const char* bb = (const char*)sStage + (ks % 3) * 24576;
        const short* cA = (const short*)bb;
        const short* cB = (const short*)(bb + 16384);
        short8 af[4], bfr[8];
        #pragma unroll
        for (int t = 0; t < 4; ++t)
            af[t] = *(const short8*)&cA[(wv * 64 + t * 16 + lr) * 32 + kc * 8];
        #pragma unroll
        for (int t = 0; t < 8; ++t)
            bfr[t] = *(const short8*)&cB[(t * 16 + lr) * 32 + kc * 8];
        #pragma unroll
        for (int i = 0; i < 4; ++i)
            #pragma unroll
            for (int j = 0; j < 8; ++j)
                acc[i][j] = __builtin_amdgcn_mfma_f32_16x16x32_bf16(af[i], bfr[j], acc[i][j], 0, 0, 0);
    }

    // ---- epilogue: LDS repack (buffer 1) -> coalesced global stores ----
    const int s = n0 >> 9;
    short* Tw = (short*)((char*)sStage + 24576) + wv * 2560;
    const int gmr = m0 + wv * 64 + lane;
    int gmrc = gmr < M ? gmr : M - 1;
    int bq = gmrc / NQ;
    int nnq = gmrc - bq * NQ;
    const int gmv = m0 + wv * 64 + (lane & 15) * 4;
    int gmvc = gmv < M ? gmv : M - 1;
    int bv2 = gmvc / NQ;
    int nnv = gmvc - bv2 * NQ;

    #pragma unroll
    for (int t = 0; t < 4; ++t) {
        const int hh = ((n0 >> 5) + t) & 15;
        float bva = ldf(biasv, n0 + t * 32 + lr, fl);
        float bvb = ldf(biasv, n0 + t * 32 + 16 + lr, fl);
        asm volatile("" ::: "memory");
        if (s == 2) {
            #pragma unroll
            for (int i = 0; i < 4; ++i) {
                int nl = i * 16 + kc * 4;
                uint2 ua = pk4(acc[i][2*t][0] + bva, acc[i][2*t][1] + bva,
                               acc[i][2*t][2] + bva, acc[i][2*t][3] + bva);
                uint2 ub = pk4(acc[i][2*t+1][0] + bvb, acc[i][2*t+1][1] + bvb,
                               acc[i][2*t+1][2] + bvb, acc[i][2*t+1][3] + bvb);
                *(uint2*)(void*)&Tw[lr * 72 + nl]        = ua;
                *(uint2*)(void*)&Tw[(16 + lr) * 72 + nl] = ub;
            }
        } else {
            float sc = (s == 0) ? QS2 : 1.0f;
            #pragma unroll
            for (int i = 0; i < 4; ++i)
                #pragma unroll
                for (int r = 0; r < 4; ++r) {
                    int nl = i * 16 + kc * 4 + r;
                    Tw[nl * 40 + lr]      = (short)f2bf((acc[i][2*t][r]   + bva) * sc);
                    Tw[nl * 40 + 16 + lr] = (short)f2bf((acc[i][2*t+1][r] + bvb) * sc);
                }
        }
        asm volatile("" ::: "memory");
        __builtin_amdgcn_s_waitcnt(0xc07f);
        asm volatile("" ::: "memory");
        if (s == 2) {
            if (gmv < M) {
                size_t bh = (size_t)(bv2 * 16 + hh);
                #pragma unroll
                for (int i2 = 0; i2 < 8; ++i2) {
                    int d = (lane >> 4) + i2 * 4;
                    uint2 u = *(const uint2*)(const void*)&Tw[d * 72 + (lane & 15) * 4];
                    *(uint2*)(void*)(Vtw + (bh * HD + d) * VSTRIDE + nnv) = u;
                }
            }
        } else {
            if (gmr < M) {
                size_t bh = (size_t)(bq * 16 + hh);
                __hip_bfloat16* dst = (s == 0 ? Qw : Kw) + (bh * NQ + nnq) * HD;
                #pragma unroll
                for (int c = 0; c < 4; ++c) {
                    short8 u = *(const short8*)(const void*)&Tw[lane * 40 + c * 8];
                    *(short8*)(void*)(dst + c * 8) = u;
                }
            }
        }
        asm volatile("" ::: "memory");
        __builtin_amdgcn_s_waitcnt(0xc07f);
        asm volatile("" ::: "memory");
    }
}

// ----- proj GEMM: 128x128, PIPELINED K-loop (3-buf, depth-2): Out=A@Bt^T+bias
__global__ __launch_bounds__(256) void gemm_bt(
    const __hip_bfloat16* __restrict__ A,
    const __hip_bfloat16* __restrict__ Bt,
    const void* __restrict__ biasv,
    int M,
    __hip_bfloat16* __restrict__ Out,
    float* __restrict__ OutF,
    const int* __restrict__ flag) {
    __shared__ __attribute__((aligned(16))) short sStage[3 * 8192];   // 48 KB
    const int tid = threadIdx.x;
    const int lane = tid & 63;
    const int wv = tid >> 6;
    const int wr = wv >> 1, wc = wv & 1;
    const int lr = lane & 15, kc = lane >> 4;
    const int m0 = blockIdx.y * 128;
    const int n0 = blockIdx.x * 128;
    const int fl = *flag;

    auto stage = [&](int s) {
        char* bb = (char*)sStage + (s % 3) * 16384;
        const int k0 = s * 32;
        #pragma unroll
        for (int it = 0; it < 2; ++it) {
            int idx = it * 256 + tid;
            int r = idx >> 2;
            int c = idx & 3;
            int gr = m0 + r; if (gr > M - 1) gr = M - 1;
            gld_lds16(A + (size_t)gr * KDIM + k0 + c * 8, bb + idx * 16);
            gld_lds16(Bt + (size_t)(n0 + r) * KDIM + k0 + c * 8, bb + 8192 + idx * 16);
        }
    };

    f32x4 acc[4][4] = {};
    stage(0);
    stage(1);

    for (int ks = 0; ks < 16; ++ks) {
        asm volatile("" ::: "memory");
        if (ks < 15) __builtin_amdgcn_s_waitcnt(0x0074);  // vmcnt(4) lgkm(0)
        else         __builtin_amdgcn_s_waitcnt(0x0070);
        __builtin_amdgcn_s_barrier();
        asm volatile("" ::: "memory");
        if (ks + 2 < 16) stage(ks + 2);

        const char* bb = (const char*)sStage + (ks % 3) * 16384;
        const short* cA = (const short*)bb;
        const short* cB = (const short*)(bb + 8192);
        short8 af[4], bfr[4];
        #pragma unroll
        for (int t = 0; t < 4; ++t)
            af[t] = *(const short8*)&cA[(wr * 64 + t * 16 + lr) * 32 + kc * 8];
        #pragma unroll
        for (int t = 0; t < 4; ++t)
            bfr[t] = *(const short8*)&cB[(wc * 64 + t * 16 + lr) * 32 + kc * 8];
        #pragma unroll
        for (int i = 0; i < 4; ++i)
            #pragma unroll
            for (int j = 0; j < 4; ++j)
                acc[i][j] = __builtin_amdgcn_mfma_f32_16x16x32_bf16(af[i], bfr[j], acc[i][j], 0, 0, 0);
    }

    #pragma unroll
    for (int i = 0; i < 4; ++i) {
        #pragma unroll
        for (int j = 0; j < 4; ++j) {
            int gn = n0 + wc * 64 + j * 16 + lr;
            float bv = ldf(biasv, gn, fl);
            #pragma unroll
            for (int r = 0; r < 4; ++r) {
                int gm = m0 + wr * 64 + i * 16 + kc * 4 + r;
                if (gm < M) {
                    float v = acc[i][j][r] + bv;
                    if (fl) OutF[(size_t)gm * CD + gn] = v;
                    else    Out[(size_t)gm * CD + gn] = __hip_bfloat16(v);
                }
            }
        }
    }
}

// ---- fused attention v14: v9 sync skeleton, 64 q-rows per wave (VERIFIED) --
__global__ __launch_bounds__(256, 3) void attn_k(
    const __hip_bfloat16* __restrict__ Qw,
    const __hip_bfloat16* __restrict__ Kw,
    const __hip_bfloat16* __restrict__ Vtw,
    const unsigned int* __restrict__ biasF,
    __hip_bfloat16* __restrict__ AO) {
    __shared__ __attribute__((aligned(16))) short sStage[3 * 2048];        // 12 KB
    __shared__ __attribute__((aligned(16))) __hip_bfloat16 Pt[4][64 * PTS]; // 20.5 KB

    const int tid = threadIdx.x;
    const int wv = tid >> 6;
    const int p = blockIdx.x * 4 + wv;       // 0..11: 64 q-rows per wave
    const int bh = blockIdx.y;               // b*16 + h
    const int hh = bh & 15;
    const int b = bh >> 4;
    const int q0 = p * 64;
    const int lane = tid & 63;
    const int lr = lane & 15, kc = lane >> 4;

    const __hip_bfloat16* Qb = Qw + (size_t)bh * NQ * HD;
    const __hip_bfloat16* Kb = Kw + (size_t)bh * NQ * HD;
    const __hip_bfloat16* Vb = Vtw + (size_t)bh * HD * VSTRIDE;
    __hip_bfloat16* Pw = &Pt[wv][0];

    short8 qfA = *(const short8*)(const void*)(Qb + (q0 + lr) * HD + kc * 8);
    short8 qfB = *(const short8*)(const void*)(Qb + (q0 + 16 + lr) * HD + kc * 8);
    short8 qfC = *(const short8*)(const void*)(Qb + (q0 + 32 + lr) * HD + kc * 8);
    short8 qfD = *(const short8*)(const void*)(Qb + (q0 + 48 + lr) * HD + kc * 8);

    short8 onesf;
    {
        short s1 = (lr == 0) ? (short)0x3F80 : (short)0;
        #pragma unroll
        for (int j = 0; j < 8; ++j) onesf[j] = s1;
    }

    // bias slices for the wave's 4 q-16-tiles: 4p+0..4p+3 (<= 47 < NQT)
    const unsigned int* bt0 = biasF + (size_t)(hh * NQT + 4 * p) * 48 * 64 + lane;
    const unsigned int* bt1 = bt0 + 48 * 64;
    const unsigned int* bt2 = bt0 + 2 * 48 * 64;
    const unsigned int* bt3 = bt0 + 3 * 48 * 64;

    unsigned int brA0[2], brA1[2], brB0[2], brB1[2];
    unsigned int brC0[2], brC1[2], brD0[2], brD1[2];
    brA0[0] = bt0[0];  brA1[0] = bt0[64];
    brB0[0] = bt1[0];  brB1[0] = bt1[64];
    brC0[0] = bt2[0];  brC1[0] = bt2[64];
    brD0[0] = bt3[0];  brD1[0] = bt3[64];

    // staging: [unit 4][row 32] blocks (transposed lane mapping). K: lanes
    // 0..127 (row=l&31, unit=l>>5); V: lanes 128..255 (d=u&31, unit=u>>5).
    // IDENTICAL to v9 (verified).
    {
        const void* src;
        if (tid < 128) src = Kb + (tid & 31) * HD + (tid >> 5) * 8;
        else { int u = tid - 128; src = Vb + (u & 31) * VSTRIDE + ((u >> 5) & 3) * 8; }
        gld_lds16(src, (char*)sStage + tid * 16);
    }
    asm volatile("" ::: "memory");

    f32x4 oa0 = {}, ob0 = {}, ol0 = {};
    f32x4 oa1 = {}, ob1 = {}, ol1 = {};
    f32x4 oa2 = {}, ob2 = {}, ol2 = {};
    f32x4 oa3 = {}, ob3 = {}, ol3 = {};

    #pragma unroll
    for (int ks = 0; ks < 24; ++ks) {
        const int cur = ks & 1, nxt = cur ^ 1;
        if (ks < 23) {
            brA0[nxt] = bt0[(2 * ks + 2) * 64];
            brA1[nxt] = bt0[(2 * ks + 3) * 64];
            brB0[nxt] = bt1[(2 * ks + 2) * 64];
            brB1[nxt] = bt1[(2 * ks + 3) * 64];
            brC0[nxt] = bt2[(2 * ks + 2) * 64];
            brC1[nxt] = bt2[(2 * ks + 3) * 64];
            brD0[nxt] = bt3[(2 * ks + 2) * 64];
            brD1[nxt] = bt3[(2 * ks + 3) * 64];
            const int k0n = (ks + 1) * 32;
            const int nb = ((ks + 1) % 3) * 4096;
            const void* src;
            if (tid < 128) src = Kb + (k0n + (tid & 31)) * HD + (tid >> 5) * 8;
            else { int u = tid - 128; src = Vb + (u & 31) * VSTRIDE + k0n + ((u >> 5) & 3) * 8; }
            gld_lds16(src, (char*)sStage + nb + tid * 16);
        }
        asm volatile("" ::: "memory");
        if (ks < 23) __builtin_amdgcn_s_waitcnt(0x0F79);   // vmcnt(9): bias(ks+1)8+stage(ks+1)1
        else         __builtin_amdgcn_s_waitcnt(0x0F70);   // vmcnt(0)
        __builtin_amdgcn_s_barrier();
        asm volatile("" ::: "memory");

        const short* sK = (const short*)((const char*)sStage + (ks % 3) * 4096);
        const short* sV = sK + 1024;
        // [unit][row]: addr = kc*256 + row*8 shorts -> 2-way banks (free)
        short8 kf0 = *(const short8*)&sK[kc * 256 + lr * 8];
        short8 kf1 = *(const short8*)&sK[kc * 256 + (16 + lr) * 8];
        short8 vf0 = *(const short8*)&sV[kc * 256 + lr * 8];
        short8 vf1 = *(const short8*)&sV[kc * 256 + (16 + lr) * 8];

        // ---- q-set 1 (tiles 4p, 4p+1) ----
        {
            f32x4 c0 = bias4f8(brA0[cur]);
            f32x4 c1 = bias4f8(brA1[cur]);
            f32x4 c2 = bias4f8(brB0[cur]);
            f32x4 c3 = bias4f8(brB1[cur]);

            c0 = __builtin_amdgcn_mfma_f32_16x16x32_bf16(kf0, qfA, c0, 0, 0, 0);
            c1 = __builtin_amdgcn_mfma_f32_16x16x32_bf16(kf1, qfA, c1, 0, 0, 0);
            c2 = __builtin_amdgcn_mfma_f32_16x16x32_bf16(kf0, qfB, c2, 0, 0, 0);
            c3 = __builtin_amdgcn_mfma_f32_16x16x32_bf16(kf1, qfB, c3, 0, 0, 0);

            #pragma unroll
            for (int r = 0; r < 4; ++r) {
                c0[r] = fexp2(c0[r]); c1[r] = fexp2(c1[r]);
                c2[r] = fexp2(c2[r]); c3[r] = fexp2(c3[r]);
            }
            pkstore(Pw + lr * PTS + kc * 4, c0);
            pkstore(Pw + lr * PTS + 16 + kc * 4, c1);
            pkstore(Pw + (16 + lr) * PTS + kc * 4, c2);
            pkstore(Pw + (16 + lr) * PTS + 16 + kc * 4, c3);
        }
        // ---- q-set 2 (tiles 4p+2, 4p+3) ----
        {
            f32x4 c0 = bias4f8(brC0[cur]);
            f32x4 c1 = bias4f8(brC1[cur]);
            f32x4 c2 = bias4f8(brD0[cur]);
            f32x4 c3 = bias4f8(brD1[cur]);

            c0 = __builtin_amdgcn_mfma_f32_16x16x32_bf16(kf0, qfC, c0, 0, 0, 0);
            c1 = __builtin_amdgcn_mfma_f32_16x16x32_bf16(kf1, qfC, c1, 0, 0, 0);
            c2 = __builtin_amdgcn_mfma_f32_16x16x32_bf16(kf0, qfD, c2, 0, 0, 0);
            c3 = __builtin_amdgcn_mfma_f32_16x16x32_bf16(kf1, qfD, c3, 0, 0, 0);

            #pragma unroll
            for (int r = 0; r < 4; ++r) {
                c0[r] = fexp2(c0[r]); c1[r] = fexp2(c1[r]);
                c2[r] = fexp2(c2[r]); c3[r] = fexp2(c3[r]);
            }
            pkstore(Pw + (32 + lr) * PTS + kc * 4, c0);
            pkstore(Pw + (32 + lr) * PTS + 16 + kc * 4, c1);
            pkstore(Pw + (48 + lr) * PTS + kc * 4, c2);
            pkstore(Pw + (48 + lr) * PTS + 16 + kc * 4, c3);
        }
        asm volatile("" ::: "memory");
        __builtin_amdgcn_s_waitcnt(0xc07f);   // lgkmcnt(0)
        asm volatile("" ::: "memory");

        short8 pfA = *(const short8*)(const void*)(Pw + lr * PTS + kc * 8);
        short8 pfB = *(const short8*)(const void*)(Pw + (16 + lr) * PTS + kc * 8);
        short8 pfC = *(const short8*)(const void*)(Pw + (32 + lr) * PTS + kc * 8);
        short8 pfD = *(const short8*)(const void*)(Pw + (48 + lr) * PTS + kc * 8);

        oa0 = __builtin_amdgcn_mfma_f32_16x16x32_bf16(pfA, vf0, oa0, 0, 0, 0);
        ob0 = __builtin_amdgcn_mfma_f32_16x16x32_bf16(pfA, vf1, ob0, 0, 0, 0);
        ol0 = __builtin_amdgcn_mfma_f32_16x16x32_bf16(pfA, onesf, ol0, 0, 0, 0);
        oa1 = __builtin_amdgcn_mfma_f32_16x16x32_bf16(pfB, vf0, oa1, 0, 0, 0);
        ob1 = __builtin_amdgcn_mfma_f32_16x16x32_bf16(pfB, vf1, ob1, 0, 0, 0);
        ol1 = __builtin_amdgcn_mfma_f32_16x16x32_bf16(pfB, onesf, ol1, 0, 0, 0);
        oa2 = __builtin_amdgcn_mfma_f32_16x16x32_bf16(pfC, vf0, oa2, 0, 0, 0);
        ob2 = __builtin_amdgcn_mfma_f32_16x16x32_bf16(pfC, vf1, ob2, 0, 0, 0);
        ol2 = __builtin_amdgcn_mfma_f32_16x16x32_bf16(pfC, onesf, ol2, 0, 0, 0);
        oa3 = __builtin_amdgcn_mfma_f32_16x16x32_bf16(pfD, vf0, oa3, 0, 0, 0);
        ob3 = __builtin_amdgcn_mfma_f32_16x16x32_bf16(pfD, vf1, ob3, 0, 0, 0);
        ol3 = __builtin_amdgcn_mfma_f32_16x16x32_bf16(pfD, onesf, ol3, 0, 0, 0);
    }

    #pragma unroll
    for (int r = 0; r < 4; ++r) {
        int row = kc * 4 + r;
        float lA = __shfl(ol0[r], lane & 48);
        float lB = __shfl(ol1[r], lane & 48);
        float lC = __shfl(ol2[r], lane & 48);
        float lD = __shfl(ol3[r], lane & 48);
        float liA = 1.0f / lA, liB = 1.0f / lB;
        float liC = 1.0f / lC, liD = 1.0f / lD;
        int orA = q0 + row, orB = q0 + 16 + row;
        int orC = q0 + 32 + row, orD = q0 + 48 + row;
        if (orA < NQ) {
            size_t base = ((size_t)b * NQ + orA) * CD + hh * HD;
            AO[base + lr]      = __hip_bfloat16(oa0[r] * liA);
            AO[base + 16 + lr] = __hip_bfloat16(ob0[r] * liA);
        }
        if (orB < NQ) {
            size_t base = ((size_t)b * NQ + orB) * CD + hh * HD;
            AO[base + lr]      = __hip_bfloat16(oa1[r] * liB);
            AO[base + 16 + lr] = __hip_bfloat16(ob1[r] * liB);
        }
        if (orC < NQ) {
            size_t base = ((size_t)b * NQ + orC) * CD + hh * HD;
            AO[base + lr]      = __hip_bfloat16(oa2[r] * liC);
            AO[base + 16 + lr] = __hip_bfloat16(ob2[r] * liC);
        }
        if (orD < NQ) {
            size_t base = ((size_t)b * NQ + orD) * CD + hh * HD;
            AO[base + lr]      = __hip_bfloat16(oa3[r] * liD);
            AO[base + 16 + lr] = __hip_bfloat16(ob3[r] * liD);
        }
    }
}

extern "C" void kernel_launch(void* const* d_in, const int* in_sizes, int n_in,
                              void* d_out, int out_size, void* d_ws, size_t ws_size,
                              hipStream_t stream) {
    char* ws = (char*)d_ws;
    size_t off = 0;
    auto carve = [&](size_t bytes) {
        char* p = ws + off;
        off += (bytes + 255) & ~(size_t)255;
        return p;
    };
    int* flagp = (int*)carve(256);
    __hip_bfloat16* Qw    = (__hip_bfloat16*)carve((size_t)256 * NQ * HD * 2);
    __hip_bfloat16* Kw    = (__hip_bfloat16*)carve((size_t)256 * NQ * HD * 2);
    __hip_bfloat16* Vtw   = (__hip_bfloat16*)carve((size_t)256 * HD * VSTRIDE * 2);
    __hip_bfloat16* WqT   = (__hip_bfloat16*)carve((size_t)1536 * 512 * 2);
    __hip_bfloat16* WpT   = (__hip_bfloat16*)carve((size_t)512 * 512 * 2);
    unsigned int*   biasF = (unsigned int*)carve((size_t)16 * NQT * 48 * 64 * 4);
    __hip_bfloat16* Xb    = (__hip_bfloat16*)carve((size_t)MROWS * CD * 2);
    __hip_bfloat16* AO    = Xb;   // attn output overwrites x-staging (dead after qkv gemm)
    (void)ws_size; (void)in_sizes; (void)n_in; (void)out_size;

    prep_k<<<dim3(PREP_CONV + PREP_TA + PREP_TB + PREP_BIAS), dim3(256), 0, stream>>>(
        d_in[0], (ushort4*)Xb, d_in[1], WqT, d_in[3], WpT,
        d_in[5], d_in[6], d_in[7], d_in[8], d_in[9], d_in[10], biasF, flagp);
    gemm_qkv<<<dim3(564), dim3(256), 0, stream>>>(Xb, WqT, d_in[2],
        Qw, Kw, Vtw, flagp);
    attn_k<<<dim3(3, 256), dim3(256), 0, stream>>>(Qw, Kw, Vtw, biasF, AO);
    gemm_bt<<<dim3(4, 93), dim3(256), 0, stream>>>(AO, WpT, d_in[4], MROWS,
        (__hip_bfloat16*)d_out, (float*)d_out, flagp);
}

// Round 11
// 196.354 us; speedup vs baseline: 1.1105x; 1.0459x over previous
//
#include <hip/hip_runtime.h>
#include <hip/hip_bf16.h>
#include <hip/hip_fp16.h>
#include <stdint.h>
#include <stddef.h>

typedef __attribute__((ext_vector_type(8))) short short8;
typedef __attribute__((ext_vector_type(4))) float f32x4;
typedef __attribute__((ext_vector_type(2))) float f32x2;
typedef unsigned short ushort_t;

#define NHEADS 16
#define HD 32
#define NQ 740
#define NB 16
#define MROWS (NB*NQ)       // 11840
#define CD 512
#define KDIM 512
#define VSTRIDE 768         // v^T row stride
#define NQT 48              // padded q-tile slots for bias
#define PTS 40              // P[q][key] stride in bf16 (32 keys + 8 pad)
#define QS2 0.2550400865f   // hd^-0.5 * log2(e)
#define LOG2E 1.4426950409f
#define NEG_BIG -43000.0f   // log2e-scaled mask; v_exp_f32 flushes to 0

static __device__ __forceinline__ void gld_lds16(const void* g, void* l) {
    __builtin_amdgcn_global_load_lds((const __attribute__((address_space(1))) void*)g,
                                     (__attribute__((address_space(3))) void*)l,
                                     16, 0, 0);
}

static __device__ __forceinline__ float ldf(const void* p, int i, int fl) {
    return fl ? ((const float*)p)[i] : (float)((const __hip_bfloat16*)p)[i];
}
static __device__ __forceinline__ ushort_t f2bf(float f) {
    __hip_bfloat16 h(f);
    return *reinterpret_cast<ushort_t*>(&h);
}
static __device__ __forceinline__ float fexp2(float x) {
#if __has_builtin(__builtin_amdgcn_exp2f)
    return __builtin_amdgcn_exp2f(x);
#else
    return exp2f(x);
#endif
}
// f32 -> e5m2 byte (RNE via fp16; e5m2 == fp16 top byte)
static __device__ __forceinline__ unsigned int f2e5(float f) {
    __half h = __float2half(f);
    unsigned short hb = *reinterpret_cast<unsigned short*>(&h);
    return (((unsigned int)hb + 0x7fu + ((hb >> 8) & 1u)) >> 8) & 0xffu;
}
// 4 packed e5m2 -> f32x4. gfx950: HW v_cvt_pk_f32_bf8 (OCP e5m2 == fp16 top byte)
#if __has_builtin(__builtin_amdgcn_cvt_pk_f32_bf8)
static __device__ __forceinline__ f32x4 bias4f8(unsigned int b) {
    f32x2 lo = __builtin_amdgcn_cvt_pk_f32_bf8((int)b, false);
    f32x2 hi = __builtin_amdgcn_cvt_pk_f32_bf8((int)b, true);
    f32x4 c;
    c[0] = lo[0]; c[1] = lo[1]; c[2] = hi[0]; c[3] = hi[1];
    return c;
}
#else
static __device__ __forceinline__ f32x4 bias4f8(unsigned int b) {
    f32x4 c;
    #pragma unroll
    for (int i = 0; i < 4; ++i) {
        union { unsigned short u; __half h; } cv;
        cv.u = (unsigned short)(((b >> (8 * i)) & 0xffu) << 8);
        c[i] = __half2float(cv.h);
    }
    return c;
}
#endif
// pack f32x4 -> 4 bf16 (RNE, packed HW cvt), single 8B LDS store
static __device__ __forceinline__ void pkstore(__hip_bfloat16* dst, f32x4 c) {
    __hip_bfloat162* d = (__hip_bfloat162*)dst;
    d[0] = __float22bfloat162_rn(make_float2(c[0], c[1]));
    d[1] = __float22bfloat162_rn(make_float2(c[2], c[3]));
}
static __device__ __forceinline__ uint2 pk4(float a, float b, float c, float d) {
    __hip_bfloat162 p01 = __float22bfloat162_rn(make_float2(a, b));
    __hip_bfloat162 p23 = __float22bfloat162_rn(make_float2(c, d));
    uint2 u;
    u.x = *reinterpret_cast<unsigned int*>(&p01);
    u.y = *reinterpret_cast<unsigned int*>(&p23);
    return u;
}

// ------- merged prep: sniff | convx | transpose Wqkv/Wproj | biasF ----------
// (verified round 10: 205.4us). Sniff folded; bias split 4x for TLP.
#define PREP_CONV 1480
#define PREP_TA   768     // Wqkv transpose: 48 x 16
#define PREP_TB   256     // Wproj transpose: 16 x 16
#define PREP_BIAS 3072    // biasF: 16*48*4 quarters
__global__ __launch_bounds__(256) void prep_k(
    const void* __restrict__ x, ushort4* __restrict__ Xb,
    const void* __restrict__ Wqkv, __hip_bfloat16* __restrict__ WqT,
    const void* __restrict__ Wproj, __hip_bfloat16* __restrict__ WpT,
    const void* __restrict__ btT, const void* __restrict__ btt,
    const void* __restrict__ ttab, const void* __restrict__ tgtab,
    const void* __restrict__ ttln, const void* __restrict__ tgln,
    unsigned int* __restrict__ biasF,
    int* __restrict__ flagp) {
    __shared__ __hip_bfloat16 tile[32][33];
    __shared__ int redf[4];
    const int bid = blockIdx.x;
    const int tid = threadIdx.x;

    // ---- folded dtype sniff: fp32 arrays have uniform high exponents ----
    int cnt = 0;
    {
        const unsigned int* wq = (const unsigned int*)Wqkv;
        for (int i = tid; i < 1024; i += 256) {
            unsigned int e = (wq[i] >> 7) & 0xFFu;
            cnt += (e > 135u) ? 1 : 0;
        }
        #pragma unroll
        for (int d = 1; d < 64; d <<= 1) cnt += __shfl_xor(cnt, d);
        if ((tid & 63) == 0) redf[tid >> 6] = cnt;
        __syncthreads();
        cnt = redf[0] + redf[1] + redf[2] + redf[3];
    }
    const int fl = (cnt > 16) ? 1 : 0;
    if (bid == 0 && tid == 0) *flagp = fl;

    if (bid < PREP_CONV) {
        const int n = MROWS * CD / 4;
        for (int i = bid * 256 + tid; i < n; i += PREP_CONV * 256) {
            if (fl) {
                float4 v = ((const float4*)x)[i];
                ushort4 o;
                o.x = f2bf(v.x); o.y = f2bf(v.y); o.z = f2bf(v.z); o.w = f2bf(v.w);
                Xb[i] = o;
            } else {
                Xb[i] = ((const ushort4*)x)[i];
            }
        }
        return;
    }
    if (bid < PREP_CONV + PREP_TA + PREP_TB) {
        const void* src; __hip_bfloat16* dst; int R, C, lb;
        if (bid < PREP_CONV + PREP_TA) {
            src = Wqkv; dst = WqT; R = 512; C = 1536; lb = bid - PREP_CONV;
        } else {
            src = Wproj; dst = WpT; R = 512; C = 512; lb = bid - PREP_CONV - PREP_TA;
        }
        int nbx = C / 32;
        int bx = (lb % nbx) * 32;
        int by = (lb / nbx) * 32;
        int tx = tid & 31, ty = tid >> 5;
        for (int r = ty; r < 32; r += 8)
            tile[r][tx] = __hip_bfloat16(ldf(src, (by + r) * C + bx + tx, fl));
        __syncthreads();
        for (int r = ty; r < 32; r += 8)
            dst[(size_t)(bx + r) * R + by + tx] = tile[tx][r];
        return;
    }
    // biasF: [blk=hh*48+qt][kb 48][lane 64] e5m2-packed uint; 12-kb quarter/block
    const int blk2 = bid - (PREP_CONV + PREP_TA + PREP_TB);
    const int hh = blk2 / 192;
    const int rem = blk2 - hh * 192;
    const int qt = rem >> 2;
    const int quarter = rem & 3;
    const size_t obase = (size_t)(hh * NQT + qt) * 48 * 64;
    for (int idx = tid; idx < 12 * 64; idx += 256) {
        const int lane = idx & 63;
        const int kb = quarter * 12 + (idx >> 6);
        const int lr = lane & 15, kc = lane >> 4;
        int i = qt * 16 + lr; if (i > NQ - 1) i = NQ - 1;
        unsigned int pk = 0;
        #pragma unroll
        for (int r = 0; r < 4; ++r) {
            int c = kb * 16 + kc * 4 + r;
            float v;
            if (c >= NQ) {
                v = NEG_BIG;
            } else if (i < 256) {
                if (c < 256) {
                    int t = ((i >> 4) - (c >> 4) + 15) * 31 + ((i & 15) - (c & 15) + 15);
                    v = ldf(btt, t * 16 + hh, fl) * LOG2E;
                } else {
                    v = (ldf(tgtab, hh * 256 + i, fl) + ldf(tgln, hh * 484 + (c - 256), fl)) * LOG2E;
                }
            } else {
                int ii = i - 256;
                if (c < 256) {
                    v = (ldf(ttab, hh * 484 + ii, fl) + ldf(ttln, hh * 256 + c, fl)) * LOG2E;
                } else {
                    int jj = c - 256;
                    int a = ii / 22, b2 = ii - a * 22;
                    int a2 = jj / 22, b3 = jj - a2 * 22;
                    int t = (a - a2 + 21) * 43 + (b2 - b3 + 21);
                    v = ldf(btT, t * 16 + hh, fl) * LOG2E;
                }
            }
            pk |= f2e5(v) << (8 * r);
        }
        biasF[obase + kb * 64 + lane] = pk;
    }
}

// ------- qkv GEMM v2: 128x128 tile (m97 geometry), 3-buf depth-2, XCD remap -
// Round-8/9 eliminated tail/drain/L2-latency as qkv's limiter; remaining model:
// 72KB LDS -> 2 blocks/CU = 8 waves/CU cannot hide the ~600-900cy/step staging
// (MfmaUtil 16% == 320 MFMA-cyc / 2100 step-cyc). 128^2 tile: 16KB/buf x3 =
// 48KB -> 3 blocks/CU = 12 waves/CU, same per-CU staging traffic, m97-measured
// structure. K-loop = gemm_bt's 8-round-verified skeleton verbatim (counted
// vmcnt(4), 3-buf). Epilogue: wave (wr,wc) owns rows wr*64+0..63 of head-
// groups {2wc,2wc+1} -> v9 epilogue with t->tg=2wc+u, wv*64->wr*64 (covers
// all 128 rows x 4 groups exactly once). Grid 93x12=1116, bijective 8-chunk
// XCD remap (140*4+139*4).
__global__ __launch_bounds__(256) void gemm_qkv(
    const __hip_bfloat16* __restrict__ A,
    const __hip_bfloat16* __restrict__ Bt,
    const void* __restrict__ biasv,
    __hip_bfloat16* __restrict__ Qw,
    __hip_bfloat16* __restrict__ Kw,
    __hip_bfloat16* __restrict__ Vtw,
    const int* __restrict__ flag) {
    __shared__ __attribute__((aligned(16))) short sStage[3 * 8192];   // 48 KB
    const int tid = threadIdx.x;
    const int lane = tid & 63;
    const int wv = tid >> 6;
    const int wr = wv >> 1, wc = wv & 1;
    const int lr = lane & 15, kc = lane >> 4;
    // XCD-chunked bijective remap over 1116 tiles (dispatch heuristic: xcd=bid&7)
    const int lin = blockIdx.x;
    const int xcd = lin & 7;
    const int cidx = lin >> 3;
    const int tile = (xcd < 4 ? xcd * 140 : 560 + (xcd - 4) * 139) + cidx;
    const int m0 = (tile / 12) * 128;
    const int n0 = (tile % 12) * 128;
    const int fl = *flag;
    const int M = MROWS;

    auto stage = [&](int s) {
        char* bb = (char*)sStage + (s % 3) * 16384;
        const int k0 = s * 32;
        #pragma unroll
        for (int it = 0; it < 2; ++it) {
            int idx = it * 256 + tid;
            int r = idx >> 2;
            int c = idx & 3;
            int gr = m0 + r; if (gr > M - 1) gr = M - 1;
            gld_lds16(A + (size_t)gr * KDIM + k0 + c * 8, bb + idx * 16);
            gld_lds16(Bt + (size_t)(n0 + r) * KDIM + k0 + c * 8, bb + 8192 + idx * 16);
        }
    };

    f32x4 acc[4][4] = {};
    stage(0);
    stage(1);

    for (int ks = 0; ks < 16; ++ks) {
        asm volatile("" ::: "memory");
        if (ks < 15) __builtin_amdgcn_s_waitcnt(0x0074);  // vmcnt(4) lgkm(0)
        else         __builtin_amdgcn_s_waitcnt(0x0070);
        __builtin_amdgcn_s_barrier();
        asm volatile("" ::: "memory");
        if (ks + 2 < 16) stage(ks + 2);

        const char* bb = (const char*)sStage + (ks % 3) * 16384;
        const short* cA = (const short*)bb;
        const short* cB = (const short*)(bb + 8192);
        short8 af[4], bfr[4];
        #pragma unroll
        for (int t = 0; t < 4; ++t)
            af[t] = *(const short8*)&cA[(wr * 64 + t * 16 + lr) * 32 + kc * 8];
        #pragma unroll
        for (int t = 0; t < 4; ++t)
            bfr[t] = *(const short8*)&cB[(wc * 64 + t * 16 + lr) * 32 + kc * 8];
        #pragma unroll
        for (int i = 0; i < 4; ++i)
            #pragma unroll
            for (int j = 0; j < 4; ++j)
                acc[i][j] = __builtin_amdgcn_mfma_f32_16x16x32_bf16(af[i], bfr[j], acc[i][j], 0, 0, 0);
    }

    // ---- epilogue: per-wave LDS repack -> coalesced global stores ----
    // acc[i][j]: row = wr*64 + i*16 + kc*4 + r, col = wc*64 + j*16 + lr.
    // Wave handles head-groups tg = 2*wc + u (u=0,1), rows wr*64 + 0..63.
    const int s = n0 >> 9;
    short* Tw = (short*)((char*)sStage + 16384) + wv * 2560;
    const int gmr = m0 + wr * 64 + lane;
    int gmrc = gmr < M ? gmr : M - 1;
    int bq = gmrc / NQ;
    int nnq = gmrc - bq * NQ;
    const int gmv = m0 + wr * 64 + (lane & 15) * 4;
    int gmvc = gmv < M ? gmv : M - 1;
    int bv2 = gmvc / NQ;
    int nnv = gmvc - bv2 * NQ;

    #pragma unroll
    for (int u = 0; u < 2; ++u) {
        const int tg = 2 * wc + u;
        const int hh = ((n0 >> 5) + tg) & 15;
        float bva = ldf(biasv, n0 + tg * 32 + lr, fl);
        float bvb = ldf(biasv, n0 + tg * 32 + 16 + lr, fl);
        asm volatile("" ::: "memory");
        if (s == 2) {
            #pragma unroll
            for (int i = 0; i < 4; ++i) {
                int nl = i * 16 + kc * 4;
                uint2 ua = pk4(acc[i][2*u][0] + bva, acc[i][2*u][1] + bva,
                               acc[i][2*u][2] + bva, acc[i][2*u][3] + bva);
                uint2 ub = pk4(acc[i][2*u+1][0] + bvb, acc[i][2*u+1][1] + bvb,
                               acc[i][2*u+1][2] + bvb, acc[i][2*u+1][3] + bvb);
                *(uint2*)(void*)&Tw[lr * 72 + nl]        = ua;
                *(uint2*)(void*)&Tw[(16 + lr) * 72 + nl] = ub;
            }
        } else {
            float sc = (s == 0) ? QS2 : 1.0f;
            #pragma unroll
            for (int i = 0; i < 4; ++i)
                #pragma unroll
                for (int r = 0; r < 4; ++r) {
                    int nl = i * 16 + kc * 4 + r;
                    Tw[nl * 40 + lr]      = (short)f2bf((acc[i][2*u][r]   + bva) * sc);
                    Tw[nl * 40 + 16 + lr] = (short)f2bf((acc[i][2*u+1][r] + bvb) * sc);
                }
        }
        asm volatile("" ::: "memory");
        __builtin_amdgcn_s_waitcnt(0xc07f);
        asm volatile("" ::: "memory");
        if (s == 2) {
            if (gmv < M) {
                size_t bh = (size_t)(bv2 * 16 + hh);
                #pragma unroll
                for (int i2 = 0; i2 < 8; ++i2) {
                    int d = (lane >> 4) + i2 * 4;
                    uint2 u2 = *(const uint2*)(const void*)&Tw[d * 72 + (lane & 15) * 4];
                    *(uint2*)(void*)(Vtw + (bh * HD + d) * VSTRIDE + nnv) = u2;
                }
            }
        } else {
            if (gmr < M) {
                size_t bh = (size_t)(bq * 16 + hh);
                __hip_bfloat16* dst = (s == 0 ? Qw : Kw) + (bh * NQ + nnq) * HD;
                #pragma unroll
                for (int c = 0; c < 4; ++c) {
                    short8 u2 = *(const short8*)(const void*)&Tw[lane * 40 + c * 8];
                    *(short8*)(void*)(dst + c * 8) = u2;
                }
            }
        }
        asm volatile("" ::: "memory");
        __builtin_amdgcn_s_waitcnt(0xc07f);
        asm volatile("" ::: "memory");
    }
}

// ----- proj GEMM: 128x128, PIPELINED K-loop (3-buf, depth-2): Out=A@Bt^T+bias
__global__ __launch_bounds__(256) void gemm_bt(
    const __hip_bfloat16* __restrict__ A,
    const __hip_bfloat16* __restrict__ Bt,
    const void* __restrict__ biasv,
    int M,
    __hip_bfloat16* __restrict__ Out,
    float* __restrict__ OutF,
    const int* __restrict__ flag) {
    __shared__ __attribute__((aligned(16))) short sStage[3 * 8192];   // 48 KB
    const int tid = threadIdx.x;
    const int lane = tid & 63;
    const int wv = tid >> 6;
    const int wr = wv >> 1, wc = wv & 1;
    const int lr = lane & 15, kc = lane >> 4;
    const int m0 = blockIdx.y * 128;
    const int n0 = blockIdx.x * 128;
    const int fl = *flag;

    auto stage = [&](int s) {
        char* bb = (char*)sStage + (s % 3) * 16384;
        const int k0 = s * 32;
        #pragma unroll
        for (int it = 0; it < 2; ++it) {
            int idx = it * 256 + tid;
            int r = idx >> 2;
            int c = idx & 3;
            int gr = m0 + r; if (gr > M - 1) gr = M - 1;
            gld_lds16(A + (size_t)gr * KDIM + k0 + c * 8, bb + idx * 16);
            gld_lds16(Bt + (size_t)(n0 + r) * KDIM + k0 + c * 8, bb + 8192 + idx * 16);
        }
    };

    f32x4 acc[4][4] = {};
    stage(0);
    stage(1);

    for (int ks = 0; ks < 16; ++ks) {
        asm volatile("" ::: "memory");
        if (ks < 15) __builtin_amdgcn_s_waitcnt(0x0074);  // vmcnt(4) lgkm(0)
        else         __builtin_amdgcn_s_waitcnt(0x0070);
        __builtin_amdgcn_s_barrier();
        asm volatile("" ::: "memory");
        if (ks + 2 < 16) stage(ks + 2);

        const char* bb = (const char*)sStage + (ks % 3) * 16384;
        const short* cA = (const short*)bb;
        const short* cB = (const short*)(bb + 8192);
        short8 af[4], bfr[4];
        #pragma unroll
        for (int t = 0; t < 4; ++t)
            af[t] = *(const short8*)&cA[(wr * 64 + t * 16 + lr) * 32 + kc * 8];
        #pragma unroll
        for (int t = 0; t < 4; ++t)
            bfr[t] = *(const short8*)&cB[(wc * 64 + t * 16 + lr) * 32 + kc * 8];
        #pragma unroll
        for (int i = 0; i < 4; ++i)
            #pragma unroll
            for (int j = 0; j < 4; ++j)
                acc[i][j] = __builtin_amdgcn_mfma_f32_16x16x32_bf16(af[i], bfr[j], acc[i][j], 0, 0, 0);
    }

    #pragma unroll
    for (int i = 0; i < 4; ++i) {
        #pragma unroll
        for (int j = 0; j < 4; ++j) {
            int gn = n0 + wc * 64 + j * 16 + lr;
            float bv = ldf(biasv, gn, fl);
            #pragma unroll
            for (int r = 0; r < 4; ++r) {
                int gm = m0 + wr * 64 + i * 16 + kc * 4 + r;
                if (gm < M) {
                    float v = acc[i][j][r] + bv;
                    if (fl) OutF[(size_t)gm * CD + gn] = v;
                    else    Out[(size_t)gm * CD + gn] = __hip_bfloat16(v);
                }
            }
        }
    }
}

// ---- fused attention v14: v9 sync skeleton, 64 q-rows per wave (VERIFIED) --
__global__ __launch_bounds__(256, 3) void attn_k(
    const __hip_bfloat16* __restrict__ Qw,
    const __hip_bfloat16* __restrict__ Kw,
    const __hip_bfloat16* __restrict__ Vtw,
    const unsigned int* __restrict__ biasF,
    __hip_bfloat16* __restrict__ AO) {
    __shared__ __attribute__((aligned(16))) short sStage[3 * 2048];        // 12 KB
    __shared__ __attribute__((aligned(16))) __hip_bfloat16 Pt[4][64 * PTS]; // 20.5 KB

    const int tid = threadIdx.x;
    const int wv = tid >> 6;
    const int p = blockIdx.x * 4 + wv;       // 0..11: 64 q-rows per wave
    const int bh = blockIdx.y;               // b*16 + h
    const int hh = bh & 15;
    const int b = bh >> 4;
    const int q0 = p * 64;
    const int lane = tid & 63;
    const int lr = lane & 15, kc = lane >> 4;

    const __hip_bfloat16* Qb = Qw + (size_t)bh * NQ * HD;
    const __hip_bfloat16* Kb = Kw + (size_t)bh * NQ * HD;
    const __hip_bfloat16* Vb = Vtw + (size_t)bh * HD * VSTRIDE;
    __hip_bfloat16* Pw = &Pt[wv][0];

    short8 qfA = *(const short8*)(const void*)(Qb + (q0 + lr) * HD + kc * 8);
    short8 qfB = *(const short8*)(const void*)(Qb + (q0 + 16 + lr) * HD + kc * 8);
    short8 qfC = *(const short8*)(const void*)(Qb + (q0 + 32 + lr) * HD + kc * 8);
    short8 qfD = *(const short8*)(const void*)(Qb + (q0 + 48 + lr) * HD + kc * 8);

    short8 onesf;
    {
        short s1 = (lr == 0) ? (short)0x3F80 : (short)0;
        #pragma unroll
        for (int j = 0; j < 8; ++j) onesf[j] = s1;
    }

    // bias slices for the wave's 4 q-16-tiles: 4p+0..4p+3 (<= 47 < NQT)
    const unsigned int* bt0 = biasF + (size_t)(hh * NQT + 4 * p) * 48 * 64 + lane;
    const unsigned int* bt1 = bt0 + 48 * 64;
    const unsigned int* bt2 = bt0 + 2 * 48 * 64;
    const unsigned int* bt3 = bt0 + 3 * 48 * 64;

    unsigned int brA0[2], brA1[2], brB0[2], brB1[2];
    unsigned int brC0[2], brC1[2], brD0[2], brD1[2];
    brA0[0] = bt0[0];  brA1[0] = bt0[64];
    brB0[0] = bt1[0];  brB1[0] = bt1[64];
    brC0[0] = bt2[0];  brC1[0] = bt2[64];
    brD0[0] = bt3[0];  brD1[0] = bt3[64];

    // staging: [unit 4][row 32] blocks (transposed lane mapping). K: lanes
    // 0..127 (row=l&31, unit=l>>5); V: lanes 128..255 (d=u&31, unit=u>>5).
    // IDENTICAL to v9 (verified).
    {
        const void* src;
        if (tid < 128) src = Kb + (tid & 31) * HD + (tid >> 5) * 8;
        else { int u = tid - 128; src = Vb + (u & 31) * VSTRIDE + ((u >> 5) & 3) * 8; }
        gld_lds16(src, (char*)sStage + tid * 16);
    }
    asm volatile("" ::: "memory");

    f32x4 oa0 = {}, ob0 = {}, ol0 = {};
    f32x4 oa1 = {}, ob1 = {}, ol1 = {};
    f32x4 oa2 = {}, ob2 = {}, ol2 = {};
    f32x4 oa3 = {}, ob3 = {}, ol3 = {};

    #pragma unroll
    for (int ks = 0; ks < 24; ++ks) {
        const int cur = ks & 1, nxt = cur ^ 1;
        if (ks < 23) {
            brA0[nxt] = bt0[(2 * ks + 2) * 64];
            brA1[nxt] = bt0[(2 * ks + 3) * 64];
            brB0[nxt] = bt1[(2 * ks + 2) * 64];
            brB1[nxt] = bt1[(2 * ks + 3) * 64];
            brC0[nxt] = bt2[(2 * ks + 2) * 64];
            brC1[nxt] = bt2[(2 * ks + 3) * 64];
            brD0[nxt] = bt3[(2 * ks + 2) * 64];
            brD1[nxt] = bt3[(2 * ks + 3) * 64];
            const int k0n = (ks + 1) * 32;
            const int nb = ((ks + 1) % 3) * 4096;
            const void* src;
            if (tid < 128) src = Kb + (k0n + (tid & 31)) * HD + (tid >> 5) * 8;
            else { int u = tid - 128; src = Vb + (u & 31) * VSTRIDE + k0n + ((u >> 5) & 3) * 8; }
            gld_lds16(src, (char*)sStage + nb + tid * 16);
        }
        asm volatile("" ::: "memory");
        if (ks < 23) __builtin_amdgcn_s_waitcnt(0x0F79);   // vmcnt(9): bias(ks+1)8+stage(ks+1)1
        else         __builtin_amdgcn_s_waitcnt(0x0F70);   // vmcnt(0)
        __builtin_amdgcn_s_barrier();
        asm volatile("" ::: "memory");

        const short* sK = (const short*)((const char*)sStage + (ks % 3) * 4096);
        const short* sV = sK + 1024;
        // [unit][row]: addr = kc*256 + row*8 shorts -> 2-way banks (free)
        short8 kf0 = *(const short8*)&sK[kc * 256 + lr * 8];
        short8 kf1 = *(const short8*)&sK[kc * 256 + (16 + lr) * 8];
        short8 vf0 = *(const short8*)&sV[kc * 256 + lr * 8];
        short8 vf1 = *(const short8*)&sV[kc * 256 + (16 + lr) * 8];

        // ---- q-set 1 (tiles 4p, 4p+1) ----
        {
            f32x4 c0 = bias4f8(brA0[cur]);
            f32x4 c1 = bias4f8(brA1[cur]);
            f32x4 c2 = bias4f8(brB0[cur]);
            f32x4 c3 = bias4f8(brB1[cur]);

            c0 = __builtin_amdgcn_mfma_f32_16x16x32_bf16(kf0, qfA, c0, 0, 0, 0);
            c1 = __builtin_amdgcn_mfma_f32_16x16x32_bf16(kf1, qfA, c1, 0, 0, 0);
            c2 = __builtin_amdgcn_mfma_f32_16x16x32_bf16(kf0, qfB, c2, 0, 0, 0);
            c3 = __builtin_amdgcn_mfma_f32_16x16x32_bf16(kf1, qfB, c3, 0, 0, 0);

            #pragma unroll
            for (int r = 0; r < 4; ++r) {
                c0[r] = fexp2(c0[r]); c1[r] = fexp2(c1[r]);
                c2[r] = fexp2(c2[r]); c3[r] = fexp2(c3[r]);
            }
            pkstore(Pw + lr * PTS + kc * 4, c0);
            pkstore(Pw + lr * PTS + 16 + kc * 4, c1);
            pkstore(Pw + (16 + lr) * PTS + kc * 4, c2);
            pkstore(Pw + (16 + lr) * PTS + 16 + kc * 4, c3);
        }
        // ---- q-set 2 (tiles 4p+2, 4p+3) ----
        {
            f32x4 c0 = bias4f8(brC0[cur]);
            f32x4 c1 = bias4f8(brC1[cur]);
            f32x4 c2 = bias4f8(brD0[cur]);
            f32x4 c3 = bias4f8(brD1[cur]);

            c0 = __builtin_amdgcn_mfma_f32_16x16x32_bf16(kf0, qfC, c0, 0, 0, 0);
            c1 = __builtin_amdgcn_mfma_f32_16x16x32_bf16(kf1, qfC, c1, 0, 0, 0);
            c2 = __builtin_amdgcn_mfma_f32_16x16x32_bf16(kf0, qfD, c2, 0, 0, 0);
            c3 = __builtin_amdgcn_mfma_f32_16x16x32_bf16(kf1, qfD, c3, 0, 0, 0);

            #pragma unroll
            for (int r = 0; r < 4; ++r) {
                c0[r] = fexp2(c0[r]); c1[r] = fexp2(c1[r]);
                c2[r] = fexp2(c2[r]); c3[r] = fexp2(c3[r]);
            }
            pkstore(Pw + (32 + lr) * PTS + kc * 4, c0);
            pkstore(Pw + (32 + lr) * PTS + 16 + kc * 4, c1);
            pkstore(Pw + (48 + lr) * PTS + kc * 4, c2);
            pkstore(Pw + (48 + lr) * PTS + 16 + kc * 4, c3);
        }
        asm volatile("" ::: "memory");
        __builtin_amdgcn_s_waitcnt(0xc07f);   // lgkmcnt(0)
        asm volatile("" ::: "memory");

        short8 pfA = *(const short8*)(const void*)(Pw + lr * PTS + kc * 8);
        short8 pfB = *(const short8*)(const void*)(Pw + (16 + lr) * PTS + kc * 8);
        short8 pfC = *(const short8*)(const void*)(Pw + (32 + lr) * PTS + kc * 8);
        short8 pfD = *(const short8*)(const void*)(Pw + (48 + lr) * PTS + kc * 8);

        oa0 = __builtin_amdgcn_mfma_f32_16x16x32_bf16(pfA, vf0, oa0, 0, 0, 0);
        ob0 = __builtin_amdgcn_mfma_f32_16x16x32_bf16(pfA, vf1, ob0, 0, 0, 0);
        ol0 = __builtin_amdgcn_mfma_f32_16x16x32_bf16(pfA, onesf, ol0, 0, 0, 0);
        oa1 = __builtin_amdgcn_mfma_f32_16x16x32_bf16(pfB, vf0, oa1, 0, 0, 0);
        ob1 = __builtin_amdgcn_mfma_f32_16x16x32_bf16(pfB, vf1, ob1, 0, 0, 0);
        ol1 = __builtin_amdgcn_mfma_f32_16x16x32_bf16(pfB, onesf, ol1, 0, 0, 0);
        oa2 = __builtin_amdgcn_mfma_f32_16x16x32_bf16(pfC, vf0, oa2, 0, 0, 0);
        ob2 = __builtin_amdgcn_mfma_f32_16x16x32_bf16(pfC, vf1, ob2, 0, 0, 0);
        ol2 = __builtin_amdgcn_mfma_f32_16x16x32_bf16(pfC, onesf, ol2, 0, 0, 0);
        oa3 = __builtin_amdgcn_mfma_f32_16x16x32_bf16(pfD, vf0, oa3, 0, 0, 0);
        ob3 = __builtin_amdgcn_mfma_f32_16x16x32_bf16(pfD, vf1, ob3, 0, 0, 0);
        ol3 = __builtin_amdgcn_mfma_f32_16x16x32_bf16(pfD, onesf, ol3, 0, 0, 0);
    }

    #pragma unroll
    for (int r = 0; r < 4; ++r) {
        int row = kc * 4 + r;
        float lA = __shfl(ol0[r], lane & 48);
        float lB = __shfl(ol1[r], lane & 48);
        float lC = __shfl(ol2[r], lane & 48);
        float lD = __shfl(ol3[r], lane & 48);
        float liA = 1.0f / lA, liB = 1.0f / lB;
        float liC = 1.0f / lC, liD = 1.0f / lD;
        int orA = q0 + row, orB = q0 + 16 + row;
        int orC = q0 + 32 + row, orD = q0 + 48 + row;
        if (orA < NQ) {
            size_t base = ((size_t)b * NQ + orA) * CD + hh * HD;
            AO[base + lr]      = __hip_bfloat16(oa0[r] * liA);
            AO[base + 16 + lr] = __hip_bfloat16(ob0[r] * liA);
        }
        if (orB < NQ) {
            size_t base = ((size_t)b * NQ + orB) * CD + hh * HD;
            AO[base + lr]      = __hip_bfloat16(oa1[r] * liB);
            AO[base + 16 + lr] = __hip_bfloat16(ob1[r] * liB);
        }
        if (orC < NQ) {
            size_t base = ((size_t)b * NQ + orC) * CD + hh * HD;
            AO[base + lr]      = __hip_bfloat16(oa2[r] * liC);
            AO[base + 16 + lr] = __hip_bfloat16(ob2[r] * liC);
        }
        if (orD < NQ) {
            size_t base = ((size_t)b * NQ + orD) * CD + hh * HD;
            AO[base + lr]      = __hip_bfloat16(oa3[r] * liD);
            AO[base + 16 + lr] = __hip_bfloat16(ob3[r] * liD);
        }
    }
}

extern "C" void kernel_launch(void* const* d_in, const int* in_sizes, int n_in,
                              void* d_out, int out_size, void* d_ws, size_t ws_size,
                              hipStream_t stream) {
    char* ws = (char*)d_ws;
    size_t off = 0;
    auto carve = [&](size_t bytes) {
        char* p = ws + off;
        off += (bytes + 255) & ~(size_t)255;
        return p;
    };
    int* flagp = (int*)carve(256);
    __hip_bfloat16* Qw    = (__hip_bfloat16*)carve((size_t)256 * NQ * HD * 2);
    __hip_bfloat16* Kw    = (__hip_bfloat16*)carve((size_t)256 * NQ * HD * 2);
    __hip_bfloat16* Vtw   = (__hip_bfloat16*)carve((size_t)256 * HD * VSTRIDE * 2);
    __hip_bfloat16* WqT   = (__hip_bfloat16*)carve((size_t)1536 * 512 * 2);
    __hip_bfloat16* WpT   = (__hip_bfloat16*)carve((size_t)512 * 512 * 2);
    unsigned int*   biasF = (unsigned int*)carve((size_t)16 * NQT * 48 * 64 * 4);
    __hip_bfloat16* Xb    = (__hip_bfloat16*)carve((size_t)MROWS * CD * 2);
    __hip_bfloat16* AO    = Xb;   // attn output overwrites x-staging (dead after qkv gemm)
    (void)ws_size; (void)in_sizes; (void)n_in; (void)out_size;

    prep_k<<<dim3(PREP_CONV + PREP_TA + PREP_TB + PREP_BIAS), dim3(256), 0, stream>>>(
        d_in[0], (ushort4*)Xb, d_in[1], WqT, d_in[3], WpT,
        d_in[5], d_in[6], d_in[7], d_in[8], d_in[9], d_in[10], biasF, flagp);
    gemm_qkv<<<dim3(1116), dim3(256), 0, stream>>>(Xb, WqT, d_in[2],
        Qw, Kw, Vtw, flagp);
    attn_k<<<dim3(3, 256), dim3(256), 0, stream>>>(Qw, Kw, Vtw, biasF, AO);
    gemm_bt<<<dim3(4, 93), dim3(256), 0, stream>>>(AO, WpT, d_in[4], MROWS,
        (__hip_bfloat16*)d_out, (float*)d_out, flagp);
}

// Round 12
// 191.462 us; speedup vs baseline: 1.1388x; 1.0256x over previous
//
#include <hip/hip_runtime.h>
#include <hip/hip_bf16.h>
#include <hip/hip_fp16.h>
#include <stdint.h>
#include <stddef.h>

typedef __attribute__((ext_vector_type(8))) short short8;
typedef __attribute__((ext_vector_type(4))) float f32x4;
typedef __attribute__((ext_vector_type(2))) float f32x2;
typedef unsigned short ushort_t;

#define NHEADS 16
#define HD 32
#define NQ 740
#define NB 16
#define MROWS (NB*NQ)       // 11840
#define CD 512
#define KDIM 512
#define VSTRIDE 768         // v^T row stride
#define NQT 48              // padded q-tile slots for bias
#define PTS 40              // P[q][key] stride in bf16 (32 keys + 8 pad)
#define QS2 0.2550400865f   // hd^-0.5 * log2(e)
#define LOG2E 1.4426950409f
#define NEG_BIG -43000.0f   // log2e-scaled mask; v_exp_f32 flushes to 0

static __device__ __forceinline__ void gld_lds16(const void* g, void* l) {
    __builtin_amdgcn_global_load_lds((const __attribute__((address_space(1))) void*)g,
                                     (__attribute__((address_space(3))) void*)l,
                                     16, 0, 0);
}

static __device__ __forceinline__ float ldf(const void* p, int i, int fl) {
    return fl ? ((const float*)p)[i] : (float)((const __hip_bfloat16*)p)[i];
}
static __device__ __forceinline__ ushort_t f2bf(float f) {
    __hip_bfloat16 h(f);
    return *reinterpret_cast<ushort_t*>(&h);
}
static __device__ __forceinline__ float fexp2(float x) {
#if __has_builtin(__builtin_amdgcn_exp2f)
    return __builtin_amdgcn_exp2f(x);
#else
    return exp2f(x);
#endif
}
// f32 -> e5m2 byte (RNE via fp16; e5m2 == fp16 top byte)
static __device__ __forceinline__ unsigned int f2e5(float f) {
    __half h = __float2half(f);
    unsigned short hb = *reinterpret_cast<unsigned short*>(&h);
    return (((unsigned int)hb + 0x7fu + ((hb >> 8) & 1u)) >> 8) & 0xffu;
}
// 4 packed e5m2 -> f32x4. gfx950: HW v_cvt_pk_f32_bf8 (OCP e5m2 == fp16 top byte)
#if __has_builtin(__builtin_amdgcn_cvt_pk_f32_bf8)
static __device__ __forceinline__ f32x4 bias4f8(unsigned int b) {
    f32x2 lo = __builtin_amdgcn_cvt_pk_f32_bf8((int)b, false);
    f32x2 hi = __builtin_amdgcn_cvt_pk_f32_bf8((int)b, true);
    f32x4 c;
    c[0] = lo[0]; c[1] = lo[1]; c[2] = hi[0]; c[3] = hi[1];
    return c;
}
#else
static __device__ __forceinline__ f32x4 bias4f8(unsigned int b) {
    f32x4 c;
    #pragma unroll
    for (int i = 0; i < 4; ++i) {
        union { unsigned short u; __half h; } cv;
        cv.u = (unsigned short)(((b >> (8 * i)) & 0xffu) << 8);
        c[i] = __half2float(cv.h);
    }
    return c;
}
#endif
// pack f32x4 -> 4 bf16 (RNE, packed HW cvt), single 8B LDS store
static __device__ __forceinline__ void pkstore(__hip_bfloat16* dst, f32x4 c) {
    __hip_bfloat162* d = (__hip_bfloat162*)dst;
    d[0] = __float22bfloat162_rn(make_float2(c[0], c[1]));
    d[1] = __float22bfloat162_rn(make_float2(c[2], c[3]));
}
static __device__ __forceinline__ uint2 pk4(float a, float b, float c, float d) {
    __hip_bfloat162 p01 = __float22bfloat162_rn(make_float2(a, b));
    __hip_bfloat162 p23 = __float22bfloat162_rn(make_float2(c, d));
    uint2 u;
    u.x = *reinterpret_cast<unsigned int*>(&p01);
    u.y = *reinterpret_cast<unsigned int*>(&p23);
    return u;
}

// ------- merged prep: sniff | convx | transpose Wqkv/Wproj | biasF ----------
// (verified round 10: 205.4us). Sniff folded; bias split 4x for TLP.
#define PREP_CONV 1480
#define PREP_TA   768     // Wqkv transpose: 48 x 16
#define PREP_TB   256     // Wproj transpose: 16 x 16
#define PREP_BIAS 3072    // biasF: 16*48*4 quarters
__global__ __launch_bounds__(256) void prep_k(
    const void* __restrict__ x, ushort4* __restrict__ Xb,
    const void* __restrict__ Wqkv, __hip_bfloat16* __restrict__ WqT,
    const void* __restrict__ Wproj, __hip_bfloat16* __restrict__ WpT,
    const void* __restrict__ btT, const void* __restrict__ btt,
    const void* __restrict__ ttab, const void* __restrict__ tgtab,
    const void* __restrict__ ttln, const void* __restrict__ tgln,
    unsigned int* __restrict__ biasF,
    int* __restrict__ flagp) {
    __shared__ __hip_bfloat16 tile[32][33];
    __shared__ int redf[4];
    const int bid = blockIdx.x;
    const int tid = threadIdx.x;

    // ---- folded dtype sniff: fp32 arrays have uniform high exponents ----
    int cnt = 0;
    {
        const unsigned int* wq = (const unsigned int*)Wqkv;
        for (int i = tid; i < 1024; i += 256) {
            unsigned int e = (wq[i] >> 7) & 0xFFu;
            cnt += (e > 135u) ? 1 : 0;
        }
        #pragma unroll
        for (int d = 1; d < 64; d <<= 1) cnt += __shfl_xor(cnt, d);
        if ((tid & 63) == 0) redf[tid >> 6] = cnt;
        __syncthreads();
        cnt = redf[0] + redf[1] + redf[2] + redf[3];
    }
    const int fl = (cnt > 16) ? 1 : 0;
    if (bid == 0 && tid == 0) *flagp = fl;

    if (bid < PREP_CONV) {
        const int n = MROWS * CD / 4;
        for (int i = bid * 256 + tid; i < n; i += PREP_CONV * 256) {
            if (fl) {
                float4 v = ((const float4*)x)[i];
                ushort4 o;
                o.x = f2bf(v.x); o.y = f2bf(v.y); o.z = f2bf(v.z); o.w = f2bf(v.w);
                Xb[i] = o;
            } else {
                Xb[i] = ((const ushort4*)x)[i];
            }
        }
        return;
    }
    if (bid < PREP_CONV + PREP_TA + PREP_TB) {
        const void* src; __hip_bfloat16* dst; int R, C, lb;
        if (bid < PREP_CONV + PREP_TA) {
            src = Wqkv; dst = WqT; R = 512; C = 1536; lb = bid - PREP_CONV;
        } else {
            src = Wproj; dst = WpT; R = 512; C = 512; lb = bid - PREP_CONV - PREP_TA;
        }
        int nbx = C / 32;
        int bx = (lb % nbx) * 32;
        int by = (lb / nbx) * 32;
        int tx = tid & 31, ty = tid >> 5;
        for (int r = ty; r < 32; r += 8)
            tile[r][tx] = __hip_bfloat16(ldf(src, (by + r) * C + bx + tx, fl));
        __syncthreads();
        for (int r = ty; r < 32; r += 8)
            dst[(size_t)(bx + r) * R + by + tx] = tile[tx][r];
        return;
    }
    // biasF: [blk=hh*48+qt][kb 48][lane 64] e5m2-packed uint; 12-kb quarter/block
    const int blk2 = bid - (PREP_CONV + PREP_TA + PREP_TB);
    const int hh = blk2 / 192;
    const int rem = blk2 - hh * 192;
    const int qt = rem >> 2;
    const int quarter = rem & 3;
    const size_t obase = (size_t)(hh * NQT + qt) * 48 * 64;
    for (int idx = tid; idx < 12 * 64; idx += 256) {
        const int lane = idx & 63;
        const int kb = quarter * 12 + (idx >> 6);
        const int lr = lane & 15, kc = lane >> 4;
        int i = qt * 16 + lr; if (i > NQ - 1) i = NQ - 1;
        unsigned int pk = 0;
        #pragma unroll
        for (int r = 0; r < 4; ++r) {
            int c = kb * 16 + kc * 4 + r;
            float v;
            if (c >= NQ) {
                v = NEG_BIG;
            } else if (i < 256) {
                if (c < 256) {
                    int t = ((i >> 4) - (c >> 4) + 15) * 31 + ((i & 15) - (c & 15) + 15);
                    v = ldf(btt, t * 16 + hh, fl) * LOG2E;
                } else {
                    v = (ldf(tgtab, hh * 256 + i, fl) + ldf(tgln, hh * 484 + (c - 256), fl)) * LOG2E;
                }
            } else {
                int ii = i - 256;
                if (c < 256) {
                    v = (ldf(ttab, hh * 484 + ii, fl) + ldf(ttln, hh * 256 + c, fl)) * LOG2E;
                } else {
                    int jj = c - 256;
                    int a = ii / 22, b2 = ii - a * 22;
                    int a2 = jj / 22, b3 = jj - a2 * 22;
                    int t = (a - a2 + 21) * 43 + (b2 - b3 + 21);
                    v = ldf(btT, t * 16 + hh, fl) * LOG2E;
                }
            }
            pk |= f2e5(v) << (8 * r);
        }
        biasF[obase + kb * 64 + lane] = pk;
    }
}

// ------- qkv GEMM v2: 128x128 tile (m97 geometry), 3-buf depth-2, XCD remap -
// (verified round 11: total 205.4 -> 196.4us). 12 waves/CU hide the staging
// latency the 256x128 tile could not.
__global__ __launch_bounds__(256) void gemm_qkv(
    const __hip_bfloat16* __restrict__ A,
    const __hip_bfloat16* __restrict__ Bt,
    const void* __restrict__ biasv,
    __hip_bfloat16* __restrict__ Qw,
    __hip_bfloat16* __restrict__ Kw,
    __hip_bfloat16* __restrict__ Vtw,
    const int* __restrict__ flag) {
    __shared__ __attribute__((aligned(16))) short sStage[3 * 8192];   // 48 KB
    const int tid = threadIdx.x;
    const int lane = tid & 63;
    const int wv = tid >> 6;
    const int wr = wv >> 1, wc = wv & 1;
    const int lr = lane & 15, kc = lane >> 4;
    // XCD-chunked bijective remap over 1116 tiles (dispatch heuristic: xcd=bid&7)
    const int lin = blockIdx.x;
    const int xcd = lin & 7;
    const int cidx = lin >> 3;
    const int tile = (xcd < 4 ? xcd * 140 : 560 + (xcd - 4) * 139) + cidx;
    const int m0 = (tile / 12) * 128;
    const int n0 = (tile % 12) * 128;
    const int fl = *flag;
    const int M = MROWS;

    auto stage = [&](int s) {
        char* bb = (char*)sStage + (s % 3) * 16384;
        const int k0 = s * 32;
        #pragma unroll
        for (int it = 0; it < 2; ++it) {
            int idx = it * 256 + tid;
            int r = idx >> 2;
            int c = idx & 3;
            int gr = m0 + r; if (gr > M - 1) gr = M - 1;
            gld_lds16(A + (size_t)gr * KDIM + k0 + c * 8, bb + idx * 16);
            gld_lds16(Bt + (size_t)(n0 + r) * KDIM + k0 + c * 8, bb + 8192 + idx * 16);
        }
    };

    f32x4 acc[4][4] = {};
    stage(0);
    stage(1);

    for (int ks = 0; ks < 16; ++ks) {
        asm volatile("" ::: "memory");
        if (ks < 15) __builtin_amdgcn_s_waitcnt(0x0074);  // vmcnt(4) lgkm(0)
        else         __builtin_amdgcn_s_waitcnt(0x0070);
        __builtin_amdgcn_s_barrier();
        asm volatile("" ::: "memory");
        if (ks + 2 < 16) stage(ks + 2);

        const char* bb = (const char*)sStage + (ks % 3) * 16384;
        const short* cA = (const short*)bb;
        const short* cB = (const short*)(bb + 8192);
        short8 af[4], bfr[4];
        #pragma unroll
        for (int t = 0; t < 4; ++t)
            af[t] = *(const short8*)&cA[(wr * 64 + t * 16 + lr) * 32 + kc * 8];
        #pragma unroll
        for (int t = 0; t < 4; ++t)
            bfr[t] = *(const short8*)&cB[(wc * 64 + t * 16 + lr) * 32 + kc * 8];
        #pragma unroll
        for (int i = 0; i < 4; ++i)
            #pragma unroll
            for (int j = 0; j < 4; ++j)
                acc[i][j] = __builtin_amdgcn_mfma_f32_16x16x32_bf16(af[i], bfr[j], acc[i][j], 0, 0, 0);
    }

    // ---- epilogue: per-wave LDS repack -> coalesced global stores ----
    // acc[i][j]: row = wr*64 + i*16 + kc*4 + r, col = wc*64 + j*16 + lr.
    // Wave handles head-groups tg = 2*wc + u (u=0,1), rows wr*64 + 0..63.
    const int s = n0 >> 9;
    short* Tw = (short*)((char*)sStage + 16384) + wv * 2560;
    const int gmr = m0 + wr * 64 + lane;
    int gmrc = gmr < M ? gmr : M - 1;
    int bq = gmrc / NQ;
    int nnq = gmrc - bq * NQ;
    const int gmv = m0 + wr * 64 + (lane & 15) * 4;
    int gmvc = gmv < M ? gmv : M - 1;
    int bv2 = gmvc / NQ;
    int nnv = gmvc - bv2 * NQ;

    #pragma unroll
    for (int u = 0; u < 2; ++u) {
        const int tg = 2 * wc + u;
        const int hh = ((n0 >> 5) + tg) & 15;
        float bva = ldf(biasv, n0 + tg * 32 + lr, fl);
        float bvb = ldf(biasv, n0 + tg * 32 + 16 + lr, fl);
        asm volatile("" ::: "memory");
        if (s == 2) {
            #pragma unroll
            for (int i = 0; i < 4; ++i) {
                int nl = i * 16 + kc * 4;
                uint2 ua = pk4(acc[i][2*u][0] + bva, acc[i][2*u][1] + bva,
                               acc[i][2*u][2] + bva, acc[i][2*u][3] + bva);
                uint2 ub = pk4(acc[i][2*u+1][0] + bvb, acc[i][2*u+1][1] + bvb,
                               acc[i][2*u+1][2] + bvb, acc[i][2*u+1][3] + bvb);
                *(uint2*)(void*)&Tw[lr * 72 + nl]        = ua;
                *(uint2*)(void*)&Tw[(16 + lr) * 72 + nl] = ub;
            }
        } else {
            float sc = (s == 0) ? QS2 : 1.0f;
            #pragma unroll
            for (int i = 0; i < 4; ++i)
                #pragma unroll
                for (int r = 0; r < 4; ++r) {
                    int nl = i * 16 + kc * 4 + r;
                    Tw[nl * 40 + lr]      = (short)f2bf((acc[i][2*u][r]   + bva) * sc);
                    Tw[nl * 40 + 16 + lr] = (short)f2bf((acc[i][2*u+1][r] + bvb) * sc);
                }
        }
        asm volatile("" ::: "memory");
        __builtin_amdgcn_s_waitcnt(0xc07f);
        asm volatile("" ::: "memory");
        if (s == 2) {
            if (gmv < M) {
                size_t bh = (size_t)(bv2 * 16 + hh);
                #pragma unroll
                for (int i2 = 0; i2 < 8; ++i2) {
                    int d = (lane >> 4) + i2 * 4;
                    uint2 u2 = *(const uint2*)(const void*)&Tw[d * 72 + (lane & 15) * 4];
                    *(uint2*)(void*)(Vtw + (bh * HD + d) * VSTRIDE + nnv) = u2;
                }
            }
        } else {
            if (gmr < M) {
                size_t bh = (size_t)(bq * 16 + hh);
                __hip_bfloat16* dst = (s == 0 ? Qw : Kw) + (bh * NQ + nnq) * HD;
                #pragma unroll
                for (int c = 0; c < 4; ++c) {
                    short8 u2 = *(const short8*)(const void*)&Tw[lane * 40 + c * 8];
                    *(short8*)(void*)(dst + c * 8) = u2;
                }
            }
        }
        asm volatile("" ::: "memory");
        __builtin_amdgcn_s_waitcnt(0xc07f);
        asm volatile("" ::: "memory");
    }
}

// ----- proj GEMM v2: 128x64 tile, 3-buf depth-2, XCD remap -----------------
// Round-11 model: bt at 128^2 had 372 blocks = 1.45 blocks/CU (~6 waves/CU) --
// LOWER TLP than qkv-v1 (43us for 1.5x the FLOPs). Same cure as qkv-v2:
// 128x64 tiles -> 744 blocks (2.9/CU), 36KB LDS (4 blocks/CU possible).
// K-loop skeleton verbatim; vmcnt rederived for 3 loads/thread/stage:
// steady-state outstanding = stage(ks+1) = 3 -> vmcnt(3). Wave wv owns rows
// wv*32..+31 (af[2]), all 64 cols (bfr[4]); coverage 128x64 exact. Epilogue =
// v1's direct stores. XCD remap: 744 = 8x93, n-fastest (A-panel's 8 consumer
// tiles on one XCD; B = 0.5MB L2-resident).
__global__ __launch_bounds__(256) void gemm_bt(
    const __hip_bfloat16* __restrict__ A,
    const __hip_bfloat16* __restrict__ Bt,
    const void* __restrict__ biasv,
    int M,
    __hip_bfloat16* __restrict__ Out,
    float* __restrict__ OutF,
    const int* __restrict__ flag) {
    __shared__ __attribute__((aligned(16))) short sStage[3 * 6144];   // 36 KB
    const int tid = threadIdx.x;
    const int lane = tid & 63;
    const int wv = tid >> 6;
    const int lr = lane & 15, kc = lane >> 4;
    // XCD-chunked bijective remap over 744 tiles (93 per XCD), n-fastest
    const int lin = blockIdx.x;
    const int xcd = lin & 7;
    const int cidx = lin >> 3;
    const int tile = xcd * 93 + cidx;
    const int m0 = (tile >> 3) * 128;
    const int n0 = (tile & 7) * 64;
    const int fl = *flag;

    auto stage = [&](int s) {
        char* bb = (char*)sStage + (s % 3) * 12288;
        const int k0 = s * 32;
        #pragma unroll
        for (int it = 0; it < 3; ++it) {
            int idx = it * 256 + tid;
            if (idx < 512) {
                int r = idx >> 2, c = idx & 3;
                int gr = m0 + r; if (gr > M - 1) gr = M - 1;
                gld_lds16(A + (size_t)gr * KDIM + k0 + c * 8, bb + idx * 16);
            } else {
                int u = idx - 512;
                int r = u >> 2, c = u & 3;
                gld_lds16(Bt + (size_t)(n0 + r) * KDIM + k0 + c * 8, bb + 8192 + u * 16);
            }
        }
    };

    f32x4 acc[2][4] = {};
    stage(0);
    stage(1);

    for (int ks = 0; ks < 16; ++ks) {
        asm volatile("" ::: "memory");
        if (ks < 15) __builtin_amdgcn_s_waitcnt(0x0073);  // vmcnt(3) lgkm(0)
        else         __builtin_amdgcn_s_waitcnt(0x0070);
        __builtin_amdgcn_s_barrier();
        asm volatile("" ::: "memory");
        if (ks + 2 < 16) stage(ks + 2);

        const char* bb = (const char*)sStage + (ks % 3) * 12288;
        const short* cA = (const short*)bb;
        const short* cB = (const short*)(bb + 8192);
        short8 af[2], bfr[4];
        #pragma unroll
        for (int t = 0; t < 2; ++t)
            af[t] = *(const short8*)&cA[(wv * 32 + t * 16 + lr) * 32 + kc * 8];
        #pragma unroll
        for (int t = 0; t < 4; ++t)
            bfr[t] = *(const short8*)&cB[(t * 16 + lr) * 32 + kc * 8];
        #pragma unroll
        for (int i = 0; i < 2; ++i)
            #pragma unroll
            for (int j = 0; j < 4; ++j)
                acc[i][j] = __builtin_amdgcn_mfma_f32_16x16x32_bf16(af[i], bfr[j], acc[i][j], 0, 0, 0);
    }

    #pragma unroll
    for (int i = 0; i < 2; ++i) {
        #pragma unroll
        for (int j = 0; j < 4; ++j) {
            int gn = n0 + j * 16 + lr;
            float bv = ldf(biasv, gn, fl);
            #pragma unroll
            for (int r = 0; r < 4; ++r) {
                int gm = m0 + wv * 32 + i * 16 + kc * 4 + r;
                if (gm < M) {
                    float v = acc[i][j][r] + bv;
                    if (fl) OutF[(size_t)gm * CD + gn] = v;
                    else    Out[(size_t)gm * CD + gn] = __hip_bfloat16(v);
                }
            }
        }
    }
}

// ---- fused attention v14: v9 sync skeleton, 64 q-rows per wave (VERIFIED) --
__global__ __launch_bounds__(256, 3) void attn_k(
    const __hip_bfloat16* __restrict__ Qw,
    const __hip_bfloat16* __restrict__ Kw,
    const __hip_bfloat16* __restrict__ Vtw,
    const unsigned int* __restrict__ biasF,
    __hip_bfloat16* __restrict__ AO) {
    __shared__ __attribute__((aligned(16))) short sStage[3 * 2048];        // 12 KB
    __shared__ __attribute__((aligned(16))) __hip_bfloat16 Pt[4][64 * PTS]; // 20.5 KB

    const int tid = threadIdx.x;
    const int wv = tid >> 6;
    const int p = blockIdx.x * 4 + wv;       // 0..11: 64 q-rows per wave
    const int bh = blockIdx.y;               // b*16 + h
    const int hh = bh & 15;
    const int b = bh >> 4;
    const int q0 = p * 64;
    const int lane = tid & 63;
    const int lr = lane & 15, kc = lane >> 4;

    const __hip_bfloat16* Qb = Qw + (size_t)bh * NQ * HD;
    const __hip_bfloat16* Kb = Kw + (size_t)bh * NQ * HD;
    const __hip_bfloat16* Vb = Vtw + (size_t)bh * HD * VSTRIDE;
    __hip_bfloat16* Pw = &Pt[wv][0];

    short8 qfA = *(const short8*)(const void*)(Qb + (q0 + lr) * HD + kc * 8);
    short8 qfB = *(const short8*)(const void*)(Qb + (q0 + 16 + lr) * HD + kc * 8);
    short8 qfC = *(const short8*)(const void*)(Qb + (q0 + 32 + lr) * HD + kc * 8);
    short8 qfD = *(const short8*)(const void*)(Qb + (q0 + 48 + lr) * HD + kc * 8);

    short8 onesf;
    {
        short s1 = (lr == 0) ? (short)0x3F80 : (short)0;
        #pragma unroll
        for (int j = 0; j < 8; ++j) onesf[j] = s1;
    }

    // bias slices for the wave's 4 q-16-tiles: 4p+0..4p+3 (<= 47 < NQT)
    const unsigned int* bt0 = biasF + (size_t)(hh * NQT + 4 * p) * 48 * 64 + lane;
    const unsigned int* bt1 = bt0 + 48 * 64;
    const unsigned int* bt2 = bt0 + 2 * 48 * 64;
    const unsigned int* bt3 = bt0 + 3 * 48 * 64;

    unsigned int brA0[2], brA1[2], brB0[2], brB1[2];
    unsigned int brC0[2], brC1[2], brD0[2], brD1[2];
    brA0[0] = bt0[0];  brA1[0] = bt0[64];
    brB0[0] = bt1[0];  brB1[0] = bt1[64];
    brC0[0] = bt2[0];  brC1[0] = bt2[64];
    brD0[0] = bt3[0];  brD1[0] = bt3[64];

    // staging: [unit 4][row 32] blocks (transposed lane mapping). K: lanes
    // 0..127 (row=l&31, unit=l>>5); V: lanes 128..255 (d=u&31, unit=u>>5).
    // IDENTICAL to v9 (verified).
    {
        const void* src;
        if (tid < 128) src = Kb + (tid & 31) * HD + (tid >> 5) * 8;
        else { int u = tid - 128; src = Vb + (u & 31) * VSTRIDE + ((u >> 5) & 3) * 8; }
        gld_lds16(src, (char*)sStage + tid * 16);
    }
    asm volatile("" ::: "memory");

    f32x4 oa0 = {}, ob0 = {}, ol0 = {};
    f32x4 oa1 = {}, ob1 = {}, ol1 = {};
    f32x4 oa2 = {}, ob2 = {}, ol2 = {};
    f32x4 oa3 = {}, ob3 = {}, ol3 = {};

    #pragma unroll
    for (int ks = 0; ks < 24; ++ks) {
        const int cur = ks & 1, nxt = cur ^ 1;
        if (ks < 23) {
            brA0[nxt] = bt0[(2 * ks + 2) * 64];
            brA1[nxt] = bt0[(2 * ks + 3) * 64];
            brB0[nxt] = bt1[(2 * ks + 2) * 64];
            brB1[nxt] = bt1[(2 * ks + 3) * 64];
            brC0[nxt] = bt2[(2 * ks + 2) * 64];
            brC1[nxt] = bt2[(2 * ks + 3) * 64];
            brD0[nxt] = bt3[(2 * ks + 2) * 64];
            brD1[nxt] = bt3[(2 * ks + 3) * 64];
            const int k0n = (ks + 1) * 32;
            const int nb = ((ks + 1) % 3) * 4096;
            const void* src;
            if (tid < 128) src = Kb + (k0n + (tid & 31)) * HD + (tid >> 5) * 8;
            else { int u = tid - 128; src = Vb + (u & 31) * VSTRIDE + k0n + ((u >> 5) & 3) * 8; }
            gld_lds16(src, (char*)sStage + nb + tid * 16);
        }
        asm volatile("" ::: "memory");
        if (ks < 23) __builtin_amdgcn_s_waitcnt(0x0F79);   // vmcnt(9): bias(ks+1)8+stage(ks+1)1
        else         __builtin_amdgcn_s_waitcnt(0x0F70);   // vmcnt(0)
        __builtin_amdgcn_s_barrier();
        asm volatile("" ::: "memory");

        const short* sK = (const short*)((const char*)sStage + (ks % 3) * 4096);
        const short* sV = sK + 1024;
        // [unit][row]: addr = kc*256 + row*8 shorts -> 2-way banks (free)
        short8 kf0 = *(const short8*)&sK[kc * 256 + lr * 8];
        short8 kf1 = *(const short8*)&sK[kc * 256 + (16 + lr) * 8];
        short8 vf0 = *(const short8*)&sV[kc * 256 + lr * 8];
        short8 vf1 = *(const short8*)&sV[kc * 256 + (16 + lr) * 8];

        // ---- q-set 1 (tiles 4p, 4p+1) ----
        {
            f32x4 c0 = bias4f8(brA0[cur]);
            f32x4 c1 = bias4f8(brA1[cur]);
            f32x4 c2 = bias4f8(brB0[cur]);
            f32x4 c3 = bias4f8(brB1[cur]);

            c0 = __builtin_amdgcn_mfma_f32_16x16x32_bf16(kf0, qfA, c0, 0, 0, 0);
            c1 = __builtin_amdgcn_mfma_f32_16x16x32_bf16(kf1, qfA, c1, 0, 0, 0);
            c2 = __builtin_amdgcn_mfma_f32_16x16x32_bf16(kf0, qfB, c2, 0, 0, 0);
            c3 = __builtin_amdgcn_mfma_f32_16x16x32_bf16(kf1, qfB, c3, 0, 0, 0);

            #pragma unroll
            for (int r = 0; r < 4; ++r) {
                c0[r] = fexp2(c0[r]); c1[r] = fexp2(c1[r]);
                c2[r] = fexp2(c2[r]); c3[r] = fexp2(c3[r]);
            }
            pkstore(Pw + lr * PTS + kc * 4, c0);
            pkstore(Pw + lr * PTS + 16 + kc * 4, c1);
            pkstore(Pw + (16 + lr) * PTS + kc * 4, c2);
            pkstore(Pw + (16 + lr) * PTS + 16 + kc * 4, c3);
        }
        // ---- q-set 2 (tiles 4p+2, 4p+3) ----
        {
            f32x4 c0 = bias4f8(brC0[cur]);
            f32x4 c1 = bias4f8(brC1[cur]);
            f32x4 c2 = bias4f8(brD0[cur]);
            f32x4 c3 = bias4f8(brD1[cur]);

            c0 = __builtin_amdgcn_mfma_f32_16x16x32_bf16(kf0, qfC, c0, 0, 0, 0);
            c1 = __builtin_amdgcn_mfma_f32_16x16x32_bf16(kf1, qfC, c1, 0, 0, 0);
            c2 = __builtin_amdgcn_mfma_f32_16x16x32_bf16(kf0, qfD, c2, 0, 0, 0);
            c3 = __builtin_amdgcn_mfma_f32_16x16x32_bf16(kf1, qfD, c3, 0, 0, 0);

            #pragma unroll
            for (int r = 0; r < 4; ++r) {
                c0[r] = fexp2(c0[r]); c1[r] = fexp2(c1[r]);
                c2[r] = fexp2(c2[r]); c3[r] = fexp2(c3[r]);
            }
            pkstore(Pw + (32 + lr) * PTS + kc * 4, c0);
            pkstore(Pw + (32 + lr) * PTS + 16 + kc * 4, c1);
            pkstore(Pw + (48 + lr) * PTS + kc * 4, c2);
            pkstore(Pw + (48 + lr) * PTS + 16 + kc * 4, c3);
        }
        asm volatile("" ::: "memory");
        __builtin_amdgcn_s_waitcnt(0xc07f);   // lgkmcnt(0)
        asm volatile("" ::: "memory");

        short8 pfA = *(const short8*)(const void*)(Pw + lr * PTS + kc * 8);
        short8 pfB = *(const short8*)(const void*)(Pw + (16 + lr) * PTS + kc * 8);
        short8 pfC = *(const short8*)(const void*)(Pw + (32 + lr) * PTS + kc * 8);
        short8 pfD = *(const short8*)(const void*)(Pw + (48 + lr) * PTS + kc * 8);

        oa0 = __builtin_amdgcn_mfma_f32_16x16x32_bf16(pfA, vf0, oa0, 0, 0, 0);
        ob0 = __builtin_amdgcn_mfma_f32_16x16x32_bf16(pfA, vf1, ob0, 0, 0, 0);
        ol0 = __builtin_amdgcn_mfma_f32_16x16x32_bf16(pfA, onesf, ol0, 0, 0, 0);
        oa1 = __builtin_amdgcn_mfma_f32_16x16x32_bf16(pfB, vf0, oa1, 0, 0, 0);
        ob1 = __builtin_amdgcn_mfma_f32_16x16x32_bf16(pfB, vf1, ob1, 0, 0, 0);
        ol1 = __builtin_amdgcn_mfma_f32_16x16x32_bf16(pfB, onesf, ol1, 0, 0, 0);
        oa2 = __builtin_amdgcn_mfma_f32_16x16x32_bf16(pfC, vf0, oa2, 0, 0, 0);
        ob2 = __builtin_amdgcn_mfma_f32_16x16x32_bf16(pfC, vf1, ob2, 0, 0, 0);
        ol2 = __builtin_amdgcn_mfma_f32_16x16x32_bf16(pfC, onesf, ol2, 0, 0, 0);
        oa3 = __builtin_amdgcn_mfma_f32_16x16x32_bf16(pfD, vf0, oa3, 0, 0, 0);
        ob3 = __builtin_amdgcn_mfma_f32_16x16x32_bf16(pfD, vf1, ob3, 0, 0, 0);
        ol3 = __builtin_amdgcn_mfma_f32_16x16x32_bf16(pfD, onesf, ol3, 0, 0, 0);
    }

    #pragma unroll
    for (int r = 0; r < 4; ++r) {
        int row = kc * 4 + r;
        float lA = __shfl(ol0[r], lane & 48);
        float lB = __shfl(ol1[r], lane & 48);
        float lC = __shfl(ol2[r], lane & 48);
        float lD = __shfl(ol3[r], lane & 48);
        float liA = 1.0f / lA, liB = 1.0f / lB;
        float liC = 1.0f / lC, liD = 1.0f / lD;
        int orA = q0 + row, orB = q0 + 16 + row;
        int orC = q0 + 32 + row, orD = q0 + 48 + row;
        if (orA < NQ) {
            size_t base = ((size_t)b * NQ + orA) * CD + hh * HD;
            AO[base + lr]      = __hip_bfloat16(oa0[r] * liA);
            AO[base + 16 + lr] = __hip_bfloat16(ob0[r] * liA);
        }
        if (orB < NQ) {
            size_t base = ((size_t)b * NQ + orB) * CD + hh * HD;
            AO[base + lr]      = __hip_bfloat16(oa1[r] * liB);
            AO[base + 16 + lr] = __hip_bfloat16(ob1[r] * liB);
        }
        if (orC < NQ) {
            size_t base = ((size_t)b * NQ + orC) * CD + hh * HD;
            AO[base + lr]      = __hip_bfloat16(oa2[r] * liC);
            AO[base + 16 + lr] = __hip_bfloat16(ob2[r] * liC);
        }
        if (orD < NQ) {
            size_t base = ((size_t)b * NQ + orD) * CD + hh * HD;
            AO[base + lr]      = __hip_bfloat16(oa3[r] * liD);
            AO[base + 16 + lr] = __hip_bfloat16(ob3[r] * liD);
        }
    }
}

extern "C" void kernel_launch(void* const* d_in, const int* in_sizes, int n_in,
                              void* d_out, int out_size, void* d_ws, size_t ws_size,
                              hipStream_t stream) {
    char* ws = (char*)d_ws;
    size_t off = 0;
    auto carve = [&](size_t bytes) {
        char* p = ws + off;
        off += (bytes + 255) & ~(size_t)255;
        return p;
    };
    int* flagp = (int*)carve(256);
    __hip_bfloat16* Qw    = (__hip_bfloat16*)carve((size_t)256 * NQ * HD * 2);
    __hip_bfloat16* Kw    = (__hip_bfloat16*)carve((size_t)256 * NQ * HD * 2);
    __hip_bfloat16* Vtw   = (__hip_bfloat16*)carve((size_t)256 * HD * VSTRIDE * 2);
    __hip_bfloat16* WqT   = (__hip_bfloat16*)carve((size_t)1536 * 512 * 2);
    __hip_bfloat16* WpT   = (__hip_bfloat16*)carve((size_t)512 * 512 * 2);
    unsigned int*   biasF = (unsigned int*)carve((size_t)16 * NQT * 48 * 64 * 4);
    __hip_bfloat16* Xb    = (__hip_bfloat16*)carve((size_t)MROWS * CD * 2);
    __hip_bfloat16* AO    = Xb;   // attn output overwrites x-staging (dead after qkv gemm)
    (void)ws_size; (void)in_sizes; (void)n_in; (void)out_size;

    prep_k<<<dim3(PREP_CONV + PREP_TA + PREP_TB + PREP_BIAS), dim3(256), 0, stream>>>(
        d_in[0], (ushort4*)Xb, d_in[1], WqT, d_in[3], WpT,
        d_in[5], d_in[6], d_in[7], d_in[8], d_in[9], d_in[10], biasF, flagp);
    gemm_qkv<<<dim3(1116), dim3(256), 0, stream>>>(Xb, WqT, d_in[2],
        Qw, Kw, Vtw, flagp);
    attn_k<<<dim3(3, 256), dim3(256), 0, stream>>>(Qw, Kw, Vtw, biasF, AO);
    gemm_bt<<<dim3(744), dim3(256), 0, stream>>>(AO, WpT, d_in[4], MROWS,
        (__hip_bfloat16*)d_out, (float*)d_out, flagp);
}